// Round 1
// baseline (1201.717 us; speedup 1.0000x reference)
//
#include <hip/hip_runtime.h>
#include <hip/hip_bf16.h>
#include <stdint.h>

#define B_    32
#define N_    1024
#define K_    256
#define OUTF_ 256

__device__ __forceinline__ float lrelu(float z) { return z > 0.f ? z : 0.2f * z; }

// ---------------- Kernel A: H[M=B*N, 256] = X[M,256] @ W[256,256] ----------------
__global__ __launch_bounds__(256) void k_gemm_h(const float* __restrict__ X,
                                                const float* __restrict__ W,
                                                float* __restrict__ H) {
  __shared__ float As[64][68];
  __shared__ float Bs[64][68];
  const int t = threadIdx.x;
  const int row0 = blockIdx.y * 64;
  const int col0 = blockIdx.x * 64;
  const int ty = t >> 4, tx = t & 15;
  float acc[4][4] = {};
  for (int kt = 0; kt < K_; kt += 64) {
#pragma unroll
    for (int rep = 0; rep < 4; ++rep) {
      const int r = rep * 16 + ty;
      const int c = tx * 4;
      *(float4*)&As[r][c] = *(const float4*)&X[(size_t)(row0 + r) * K_ + kt + c];
      *(float4*)&Bs[r][c] = *(const float4*)&W[(size_t)(kt + r) * OUTF_ + col0 + c];
    }
    __syncthreads();
#pragma unroll
    for (int k = 0; k < 64; ++k) {
      const float4 b4 = *(const float4*)&Bs[k][tx * 4];
      float a[4];
#pragma unroll
      for (int q = 0; q < 4; ++q) a[q] = As[ty * 4 + q][k];
#pragma unroll
      for (int q = 0; q < 4; ++q) {
        acc[q][0] = fmaf(a[q], b4.x, acc[q][0]);
        acc[q][1] = fmaf(a[q], b4.y, acc[q][1]);
        acc[q][2] = fmaf(a[q], b4.z, acc[q][2]);
        acc[q][3] = fmaf(a[q], b4.w, acc[q][3]);
      }
    }
    __syncthreads();
  }
#pragma unroll
  for (int q = 0; q < 4; ++q) {
    const float4 o = make_float4(acc[q][0], acc[q][1], acc[q][2], acc[q][3]);
    *(float4*)&H[(size_t)(row0 + ty * 4 + q) * OUTF_ + col0 + tx * 4] = o;
  }
}

// ---------------- Kernel B: el/er per (b,n,h): dot(h_row, attn_l/r) ----------------
__global__ __launch_bounds__(256) void k_elr(const float* __restrict__ H,
                                             const float* __restrict__ AL,
                                             const float* __restrict__ AR,
                                             float* __restrict__ EL,
                                             float* __restrict__ ER) {
  const int t = threadIdx.x;
  const int wave = t >> 6, lane = t & 63;
  const int idx = blockIdx.x * 4 + wave;  // b*N + n, 0..32767
  const float* hrow = H + (size_t)idx * OUTF_;
#pragma unroll
  for (int h = 0; h < 4; ++h) {
    const float v = hrow[h * 64 + lane];
    float dl = v * AL[h * 64 + lane];
    float dr = v * AR[h * 64 + lane];
#pragma unroll
    for (int s = 32; s > 0; s >>= 1) { dl += __shfl_xor(dl, s); dr += __shfl_xor(dr, s); }
    if (lane == 0) { EL[idx * 4 + h] = dl; ER[idx * 4 + h] = dr; }
  }
}

// ---------------- Kernel C: bitmask from adj + masked row-max -> m[b,i,h] ----------------
// m = max_j logits[j] where logits = mask ? lrelu(el_i + er_j) : -1e9.
// LeakyReLU is monotone => masked max of lrelu(el+er_j) = lrelu(el + masked max er_j).
__global__ __launch_bounds__(256) void k_maskmax(const float* __restrict__ ADJ,
                                                 const float* __restrict__ ER,
                                                 const float* __restrict__ EL,
                                                 unsigned long long* __restrict__ MASK,
                                                 float* __restrict__ M) {
  const int t = threadIdx.x;
  const int wave = t >> 6, lane = t & 63;
  const int row = blockIdx.x * 4 + wave;  // b*N + i
  const int b = row >> 10;
  const float* arow = ADJ + (size_t)row * N_;
  const float4* ER4 = (const float4*)ER;
  float mx[4] = {-3e38f, -3e38f, -3e38f, -3e38f};
  unsigned long long any = 0ull;
  for (int w = 0; w < 16; ++w) {
    const int j = w * 64 + lane;
    const float a = arow[j];
    const bool val = a > 0.5f;
    const unsigned long long bits = __ballot(val);
    if (lane == 0) MASK[(size_t)row * 16 + w] = bits;
    any |= bits;
    const float4 e4 = ER4[b * N_ + j];
    if (val) {
      mx[0] = fmaxf(mx[0], e4.x);
      mx[1] = fmaxf(mx[1], e4.y);
      mx[2] = fmaxf(mx[2], e4.z);
      mx[3] = fmaxf(mx[3], e4.w);
    }
  }
#pragma unroll
  for (int h = 0; h < 4; ++h) {
#pragma unroll
    for (int s = 32; s > 0; s >>= 1) mx[h] = fmaxf(mx[h], __shfl_xor(mx[h], s));
  }
  if (lane < 4) {
    const int h = lane;
    const float elv = EL[row * 4 + h];
    const float m = (any != 0ull) ? lrelu(elv + mx[h]) : -1e9f;
    M[row * 4 + h] = m;
  }
}

// ---------------- Kernel D: fused softmax-numerator aggregation + epilogue ----------------
// Block: one b, 32 rows of i, all heads. Wave = head, lane = feature f.
// Unnormalized p staged in LDS; acc[i] += p * h[j]; divide by sum(p) at end.
__global__ __launch_bounds__(256) void k_agg(const float* __restrict__ HG,
                                             const float* __restrict__ ER,
                                             const float* __restrict__ EL,
                                             const float* __restrict__ M,
                                             const unsigned long long* __restrict__ MASK,
                                             const float* __restrict__ X,
                                             const float* __restrict__ BIAS,
                                             float* __restrict__ OUT) {
  __shared__ unsigned long long mask_s[32][16];
  __shared__ float el_s[32][4];
  __shared__ float m_s[32][4];
  __shared__ float psum_s[32][4];
  __shared__ float p_s[4][32][32];

  const int t = threadIdx.x;
  const int bid = blockIdx.x;
  const int b = bid & 31;            // blockIdx % 32 == b -> same b lands on same XCD
  const int i0 = (bid >> 5) * 32;
  const int h = t >> 6, f = t & 63;  // wave-uniform head
  const size_t base_row = (size_t)b * N_ + i0;
  const size_t base_b = (size_t)b * N_;

#pragma unroll
  for (int r = 0; r < 2; ++r) {
    const int idx = t + r * 256;  // 0..511
    const int ri = idx >> 4, w = idx & 15;
    mask_s[ri][w] = MASK[(base_row + ri) * 16 + w];
  }
  if (t < 128) {
    const int ri = t >> 2, hh = t & 3;
    el_s[ri][hh] = EL[(base_row + ri) * 4 + hh];
    m_s[ri][hh]  = M[(base_row + ri) * 4 + hh];
    psum_s[ri][hh] = 0.f;
  }
  float acc[32];
#pragma unroll
  for (int i = 0; i < 32; ++i) acc[i] = 0.f;
  __syncthreads();

  const float4* ER4 = (const float4*)ER;
  const int ip = t >> 3, sub = t & 7;  // p-compute: thread covers (i=ip, j=sub*4..+3, all h)

  for (int j0 = 0; j0 < N_; j0 += 32) {
    // ---- p compute ----
    const unsigned long long mw = mask_s[ip][j0 >> 6];
    const unsigned int mb32 = (unsigned int)((mw >> (j0 & 32)) & 0xffffffffull);
    float e4a[4][4];
#pragma unroll
    for (int jj = 0; jj < 4; ++jj) {
      const float4 tmp = ER4[b * N_ + j0 + sub * 4 + jj];
      e4a[jj][0] = tmp.x; e4a[jj][1] = tmp.y; e4a[jj][2] = tmp.z; e4a[jj][3] = tmp.w;
    }
#pragma unroll
    for (int hh = 0; hh < 4; ++hh) {
      const float elh = el_s[ip][hh];
      const float mh  = m_s[ip][hh];
      float ph[4];
#pragma unroll
      for (int jj = 0; jj < 4; ++jj) {
        float z = elh + e4a[jj][hh];
        z = z > 0.f ? z : 0.2f * z;
        const float logit = ((mb32 >> (sub * 4 + jj)) & 1u) ? z : -1e9f;
        ph[jj] = __expf(logit - mh);  // invalid j: exp(-1e9-m) -> 0 (or 1 if m==-1e9: uniform)
      }
      *(float4*)&p_s[hh][ip][sub * 4] = make_float4(ph[0], ph[1], ph[2], ph[3]);
    }
    __syncthreads();

    // ---- psum (t<128: one (i,h) each) ----
    if (t < 128) {
      const int ri = t >> 2, hh = t & 3;
      float s = 0.f;
      const float4* pr = (const float4*)&p_s[hh][ri][0];
#pragma unroll
      for (int jv = 0; jv < 8; ++jv) { const float4 v = pr[jv]; s += (v.x + v.y) + (v.z + v.w); }
      psum_s[ri][hh] += s;
    }

    // ---- load h values for this chunk (register-resident) ----
    float hv[32];
#pragma unroll
    for (int jj = 0; jj < 32; ++jj)
      hv[jj] = HG[(base_b + (size_t)(j0 + jj)) * OUTF_ + h * 64 + f];

    // ---- aggregate: acc[i] += p[h][i][j] * hv[j]; p reads are wave-broadcast ----
#pragma unroll
    for (int i = 0; i < 32; ++i) {
      const float4* pr = (const float4*)&p_s[h][i][0];
#pragma unroll
      for (int jv = 0; jv < 8; ++jv) {
        const float4 pv = pr[jv];
        acc[i] = fmaf(pv.x, hv[jv * 4 + 0], acc[i]);
        acc[i] = fmaf(pv.y, hv[jv * 4 + 1], acc[i]);
        acc[i] = fmaf(pv.z, hv[jv * 4 + 2], acc[i]);
        acc[i] = fmaf(pv.w, hv[jv * 4 + 3], acc[i]);
      }
    }
    __syncthreads();
  }

  // ---- epilogue: normalize + bias + residual + ELU ----
#pragma unroll
  for (int i = 0; i < 32; ++i) {
    const float s = psum_s[i][h];
    const size_t off = (base_row + i) * OUTF_ + h * 64 + f;
    float o = acc[i] / s + BIAS[h * 64 + f] + X[off];
    o = o > 0.f ? o : __expf(o) - 1.f;
    OUT[off] = o;
  }
}

extern "C" void kernel_launch(void* const* d_in, const int* in_sizes, int n_in,
                              void* d_out, int out_size, void* d_ws, size_t ws_size,
                              hipStream_t stream) {
  const float* ADJ  = (const float*)d_in[0];
  const float* X    = (const float*)d_in[1];
  const float* W    = (const float*)d_in[2];
  const float* AL   = (const float*)d_in[3];
  const float* AR   = (const float*)d_in[4];
  const float* BIAS = (const float*)d_in[5];
  float* OUT = (float*)d_out;

  char* ws = (char*)d_ws;
  float* H = (float*)ws;
  size_t off = (size_t)B_ * N_ * OUTF_ * sizeof(float);        // 32 MiB
  float* EL = (float*)(ws + off); off += (size_t)B_ * N_ * 4 * sizeof(float);
  float* ER = (float*)(ws + off); off += (size_t)B_ * N_ * 4 * sizeof(float);
  float* M  = (float*)(ws + off); off += (size_t)B_ * N_ * 4 * sizeof(float);
  unsigned long long* MASK = (unsigned long long*)(ws + off);  // 4 MiB

  k_gemm_h<<<dim3(4, 512), 256, 0, stream>>>(X, W, H);
  k_elr<<<8192, 256, 0, stream>>>(H, AL, AR, EL, ER);
  k_maskmax<<<8192, 256, 0, stream>>>(ADJ, ER, EL, MASK, M);
  k_agg<<<1024, 256, 0, stream>>>(H, ER, EL, M, MASK, X, BIAS, OUT);
}

// Round 2
// 287.480 us; speedup vs baseline: 4.1802x; 4.1802x over previous
//
#include <hip/hip_runtime.h>
#include <hip/hip_bf16.h>
#include <stdint.h>

#define B_    32
#define N_    1024
#define K_    256
#define OUTF_ 256

typedef __attribute__((ext_vector_type(4))) float f32x4;
typedef __attribute__((ext_vector_type(8))) short bf16x8;

__device__ __forceinline__ float lrelu(float z) { return z > 0.f ? z : 0.2f * z; }

__device__ __forceinline__ unsigned short f2bf(float x) {
  union { float f; unsigned int u; } v; v.f = x;
  const unsigned int r = v.u + 0x7fffu + ((v.u >> 16) & 1u);  // RNE; no NaN inputs here
  return (unsigned short)(r >> 16);
}

// ---------------- Kernel A: H = X @ W, emitted as HbT[b*4+h][f=64][j=N] bf16 (transposed),
// plus fused el/er reductions -> ELt/ERt[b*4+h][N] f32. No f32 H buffer at all. ----------------
__global__ __launch_bounds__(256) void k_gemm_h(const float* __restrict__ X,
                                                const float* __restrict__ W,
                                                const float* __restrict__ AL,
                                                const float* __restrict__ AR,
                                                unsigned short* __restrict__ HbT,
                                                float* __restrict__ ELt,
                                                float* __restrict__ ERt) {
  __shared__ float As[64][68];
  __shared__ float Bs[64][68];
  const int t = threadIdx.x;
  const int row0 = blockIdx.y * 64;   // b*N + i base
  const int h    = blockIdx.x;        // head; col0 = h*64 covers exactly this head
  const int col0 = h * 64;
  const int ty = t >> 4, tx = t & 15;
  float acc[4][4] = {};
  for (int kt = 0; kt < K_; kt += 64) {
#pragma unroll
    for (int rep = 0; rep < 4; ++rep) {
      const int rr = rep * 16 + ty;
      const int cc = tx * 4;
      *(float4*)&As[rr][cc] = *(const float4*)&X[(size_t)(row0 + rr) * K_ + kt + cc];
      *(float4*)&Bs[rr][cc] = *(const float4*)&W[(size_t)(kt + rr) * OUTF_ + col0 + cc];
    }
    __syncthreads();
#pragma unroll
    for (int k = 0; k < 64; ++k) {
      const float4 b4 = *(const float4*)&Bs[k][tx * 4];
      float a[4];
#pragma unroll
      for (int q = 0; q < 4; ++q) a[q] = As[ty * 4 + q][k];
#pragma unroll
      for (int q = 0; q < 4; ++q) {
        acc[q][0] = fmaf(a[q], b4.x, acc[q][0]);
        acc[q][1] = fmaf(a[q], b4.y, acc[q][1]);
        acc[q][2] = fmaf(a[q], b4.z, acc[q][2]);
        acc[q][3] = fmaf(a[q], b4.w, acc[q][3]);
      }
    }
    __syncthreads();
  }
  const int b  = row0 >> 10;
  const int ib = row0 & (N_ - 1);
  const int bh = b * 4 + h;

  // fused el/er: this block holds all 64 features of head h for rows ib..ib+63
  float pl[4] = {}, pr[4] = {};
#pragma unroll
  for (int q = 0; q < 4; ++q)
#pragma unroll
    for (int c = 0; c < 4; ++c) {
      const int fl = tx * 4 + c;
      pl[q] = fmaf(acc[q][c], AL[col0 + fl], pl[q]);
      pr[q] = fmaf(acc[q][c], AR[col0 + fl], pr[q]);
    }
#pragma unroll
  for (int s = 1; s < 16; s <<= 1) {
#pragma unroll
    for (int q = 0; q < 4; ++q) { pl[q] += __shfl_xor(pl[q], s); pr[q] += __shfl_xor(pr[q], s); }
  }
  if (tx == 0) {
#pragma unroll
    for (int q = 0; q < 4; ++q) {
      ELt[(size_t)bh * N_ + ib + ty * 4 + q] = pl[q];
      ERt[(size_t)bh * N_ + ib + ty * 4 + q] = pr[q];
    }
  }
  // transposed bf16 store: HbT[bh][f][j]; acc[q][c] -> f = tx*4+c, j = ib + ty*4 + q
#pragma unroll
  for (int c = 0; c < 4; ++c) {
    ushort4 o;
    o.x = f2bf(acc[0][c]); o.y = f2bf(acc[1][c]); o.z = f2bf(acc[2][c]); o.w = f2bf(acc[3][c]);
    *(ushort4*)&HbT[(size_t)bh * (64 * N_) + (size_t)(tx * 4 + c) * N_ + ib + ty * 4] = o;
  }
}

// ---------------- Kernel B: adj -> bitmask + masked row-max -> Mt[bh][i] ----------------
__global__ __launch_bounds__(256) void k_maskmax(const float* __restrict__ ADJ,
                                                 const float* __restrict__ ERt,
                                                 const float* __restrict__ ELt,
                                                 unsigned long long* __restrict__ MASK,
                                                 float* __restrict__ Mt) {
  const int t = threadIdx.x;
  const int wave = t >> 6, lane = t & 63;
  const int row = blockIdx.x * 4 + wave;  // b*N + i
  const int b = row >> 10, i = row & (N_ - 1);
  const float* arow = ADJ + (size_t)row * N_;
  float mx[4] = {-3e38f, -3e38f, -3e38f, -3e38f};
  unsigned long long any = 0ull;
  for (int w = 0; w < 16; ++w) {
    const int j = w * 64 + lane;
    const bool val = arow[j] > 0.5f;
    const unsigned long long bits = __ballot(val);
    if (lane == 0) MASK[(size_t)row * 16 + w] = bits;
    any |= bits;
#pragma unroll
    for (int hh = 0; hh < 4; ++hh) {
      const float e = ERt[(size_t)(b * 4 + hh) * N_ + j];
      if (val) mx[hh] = fmaxf(mx[hh], e);
    }
  }
#pragma unroll
  for (int hh = 0; hh < 4; ++hh)
#pragma unroll
    for (int s = 32; s > 0; s >>= 1) mx[hh] = fmaxf(mx[hh], __shfl_xor(mx[hh], s));
  if (lane < 4) {
    const float elv = ELt[(size_t)(b * 4 + lane) * N_ + i];
    Mt[(size_t)(b * 4 + lane) * N_ + i] = (any != 0ull) ? lrelu(elv + mx[lane]) : -1e9f;
  }
}

// ---------------- Kernel C: MFMA aggregation (flash-attn PV style), no LDS ----------------
// Block: (b, h, 128-row i-tile), 4 waves; wave owns 32 i-rows x 64 f.
// A-frag (p) computed in registers in MFMA layout: row = lane&15, k = (lane>>4)*8 + e.
// B-frag (h) read as contiguous bf16x8 from HbT[bh][f][j]. Unnormalized accumulate; /= sum(p).
__global__ __launch_bounds__(256) void k_agg(const unsigned short* __restrict__ HbT,
                                             const float* __restrict__ ERt,
                                             const float* __restrict__ ELt,
                                             const float* __restrict__ Mt,
                                             const unsigned long long* __restrict__ MASK,
                                             const float* __restrict__ X,
                                             const float* __restrict__ BIAS,
                                             float* __restrict__ OUT) {
  const int t = threadIdx.x;
  const int lane = t & 63, w = t >> 6;
  const int bid = blockIdx.x;
  const int b = bid & 31;            // same b -> same XCD residency for its 512KB panel
  const int h = (bid >> 5) & 3;
  const int it = bid >> 7;           // 0..7
  const int bh = b * 4 + h;
  const int i0 = it * 128 + w * 32;
  const int r = lane & 15, kg = lane >> 4;
  const int iA0 = i0 + r;
  const int iA1 = i0 + 16 + r;

  const float el0 = ELt[(size_t)bh * N_ + iA0], m0 = Mt[(size_t)bh * N_ + iA0];
  const float el1 = ELt[(size_t)bh * N_ + iA1], m1 = Mt[(size_t)bh * N_ + iA1];
  const unsigned long long* mrow0 = MASK + (size_t)(b * N_ + iA0) * 16;
  const unsigned long long* mrow1 = MASK + (size_t)(b * N_ + iA1) * 16;
  const unsigned short* hp = HbT + (size_t)bh * (64 * N_);
  const float* erp = ERt + (size_t)bh * N_;

  const f32x4 zero4 = {0.f, 0.f, 0.f, 0.f};
  f32x4 acc0[4], acc1[4];
#pragma unroll
  for (int c = 0; c < 4; ++c) { acc0[c] = zero4; acc1[c] = zero4; }
  float ps0 = 0.f, ps1 = 0.f;

  for (int j64 = 0; j64 < N_; j64 += 64) {
    const unsigned long long mw0 = mrow0[j64 >> 6];
    const unsigned long long mw1 = mrow1[j64 >> 6];
#pragma unroll
    for (int half = 0; half < 2; ++half) {
      const int jb = j64 + half * 32 + kg * 8;
      const int sh = half * 32 + kg * 8;
      const unsigned int bits0 = (unsigned int)(mw0 >> sh) & 0xffu;
      const unsigned int bits1 = (unsigned int)(mw1 >> sh) & 0xffu;
      const float4 ea = *(const float4*)&erp[jb];
      const float4 eb = *(const float4*)&erp[jb + 4];
      const float er8[8] = {ea.x, ea.y, ea.z, ea.w, eb.x, eb.y, eb.z, eb.w};
      union { bf16x8 v; unsigned short s[8]; } a0, a1;
#pragma unroll
      for (int e = 0; e < 8; ++e) {
        float z0 = el0 + er8[e];
        z0 = z0 > 0.f ? z0 : 0.2f * z0;
        z0 = ((bits0 >> e) & 1u) ? z0 : -1e9f;
        const float p0 = __expf(z0 - m0);   // all-masked row: m=-1e9 -> exp(0)=1 (uniform), matches jax
        ps0 += p0; a0.s[e] = f2bf(p0);
        float z1 = el1 + er8[e];
        z1 = z1 > 0.f ? z1 : 0.2f * z1;
        z1 = ((bits1 >> e) & 1u) ? z1 : -1e9f;
        const float p1 = __expf(z1 - m1);
        ps1 += p1; a1.s[e] = f2bf(p1);
      }
#pragma unroll
      for (int c = 0; c < 4; ++c) {
        const bf16x8 bv = *(const bf16x8*)&hp[(size_t)(c * 16 + r) * N_ + jb];
        acc0[c] = __builtin_amdgcn_mfma_f32_16x16x32_bf16(a0.v, bv, acc0[c], 0, 0, 0);
        acc1[c] = __builtin_amdgcn_mfma_f32_16x16x32_bf16(a1.v, bv, acc1[c], 0, 0, 0);
      }
    }
  }
  ps0 += __shfl_xor(ps0, 16); ps0 += __shfl_xor(ps0, 32);
  ps1 += __shfl_xor(ps1, 16); ps1 += __shfl_xor(ps1, 32);

  // epilogue: C/D layout col = lane&15, row = (lane>>4)*4 + reg (verified m89)
#pragma unroll
  for (int reg = 0; reg < 4; ++reg) {
    const int ir = kg * 4 + reg;
    const float d0 = __shfl(ps0, ir);   // lane ir holds psum for row i0+ir
    const float d1 = __shfl(ps1, ir);
    const int gi0 = b * N_ + i0 + ir;
    const int gi1 = gi0 + 16;
#pragma unroll
    for (int c = 0; c < 4; ++c) {
      const int f = h * 64 + c * 16 + r;
      const size_t off0 = (size_t)gi0 * OUTF_ + f;
      const size_t off1 = (size_t)gi1 * OUTF_ + f;
      float o0 = acc0[c][reg] / d0 + BIAS[f] + X[off0];
      o0 = o0 > 0.f ? o0 : __expf(o0) - 1.f;
      OUT[off0] = o0;
      float o1 = acc1[c][reg] / d1 + BIAS[f] + X[off1];
      o1 = o1 > 0.f ? o1 : __expf(o1) - 1.f;
      OUT[off1] = o1;
    }
  }
}

extern "C" void kernel_launch(void* const* d_in, const int* in_sizes, int n_in,
                              void* d_out, int out_size, void* d_ws, size_t ws_size,
                              hipStream_t stream) {
  const float* ADJ  = (const float*)d_in[0];
  const float* X    = (const float*)d_in[1];
  const float* W    = (const float*)d_in[2];
  const float* AL   = (const float*)d_in[3];
  const float* AR   = (const float*)d_in[4];
  const float* BIAS = (const float*)d_in[5];
  float* OUT = (float*)d_out;

  char* ws = (char*)d_ws;
  unsigned short* HbT = (unsigned short*)ws;                       // 16 MiB bf16 [128][64][1024]
  size_t off = (size_t)B_ * 4 * 64 * N_ * sizeof(unsigned short);
  float* ELt = (float*)(ws + off); off += (size_t)B_ * 4 * N_ * sizeof(float);
  float* ERt = (float*)(ws + off); off += (size_t)B_ * 4 * N_ * sizeof(float);
  float* Mt  = (float*)(ws + off); off += (size_t)B_ * 4 * N_ * sizeof(float);
  unsigned long long* MASK = (unsigned long long*)(ws + off);      // 4 MiB

  k_gemm_h<<<dim3(4, 512), 256, 0, stream>>>(X, W, AL, AR, HbT, ELt, ERt);
  k_maskmax<<<8192, 256, 0, stream>>>(ADJ, ERt, ELt, MASK, Mt);
  k_agg<<<1024, 256, 0, stream>>>(HbT, ERt, ELt, Mt, MASK, X, BIAS, OUT);
}

// Round 3
// 189.936 us; speedup vs baseline: 6.3270x; 1.5136x over previous
//
#include <hip/hip_runtime.h>
#include <hip/hip_bf16.h>
#include <stdint.h>

#define B_    32
#define N_    1024
#define K_    256
#define OUTF_ 256

typedef __attribute__((ext_vector_type(4))) float f32x4;
typedef __attribute__((ext_vector_type(8))) short bf16x8;

__device__ __forceinline__ float lrelu(float z) { return z > 0.f ? z : 0.2f * z; }

__device__ __forceinline__ unsigned short f2bf(float x) {
  union { float f; unsigned int u; } v; v.f = x;
  const unsigned int r = v.u + 0x7fffu + ((v.u >> 16) & 1u);  // RNE; no NaN inputs here
  return (unsigned short)(r >> 16);
}

// ---------------- Kernel A: H = X @ W, emitted as HbT[b*4+h][f=64][j=N] bf16 (transposed),
// plus fused el/er reductions -> ELt/ERt[b*4+h][N] f32. No f32 H buffer at all. ----------------
__global__ __launch_bounds__(256) void k_gemm_h(const float* __restrict__ X,
                                                const float* __restrict__ W,
                                                const float* __restrict__ AL,
                                                const float* __restrict__ AR,
                                                unsigned short* __restrict__ HbT,
                                                float* __restrict__ ELt,
                                                float* __restrict__ ERt) {
  __shared__ float As[64][68];
  __shared__ float Bs[64][68];
  const int t = threadIdx.x;
  const int row0 = blockIdx.y * 64;   // b*N + i base
  const int h    = blockIdx.x;        // head; col0 = h*64 covers exactly this head
  const int col0 = h * 64;
  const int ty = t >> 4, tx = t & 15;
  float acc[4][4] = {};
  for (int kt = 0; kt < K_; kt += 64) {
#pragma unroll
    for (int rep = 0; rep < 4; ++rep) {
      const int rr = rep * 16 + ty;
      const int cc = tx * 4;
      *(float4*)&As[rr][cc] = *(const float4*)&X[(size_t)(row0 + rr) * K_ + kt + cc];
      *(float4*)&Bs[rr][cc] = *(const float4*)&W[(size_t)(kt + rr) * OUTF_ + col0 + cc];
    }
    __syncthreads();
#pragma unroll
    for (int k = 0; k < 64; ++k) {
      const float4 b4 = *(const float4*)&Bs[k][tx * 4];
      float a[4];
#pragma unroll
      for (int q = 0; q < 4; ++q) a[q] = As[ty * 4 + q][k];
#pragma unroll
      for (int q = 0; q < 4; ++q) {
        acc[q][0] = fmaf(a[q], b4.x, acc[q][0]);
        acc[q][1] = fmaf(a[q], b4.y, acc[q][1]);
        acc[q][2] = fmaf(a[q], b4.z, acc[q][2]);
        acc[q][3] = fmaf(a[q], b4.w, acc[q][3]);
      }
    }
    __syncthreads();
  }
  const int b  = row0 >> 10;
  const int ib = row0 & (N_ - 1);
  const int bh = b * 4 + h;

  // fused el/er: this block holds all 64 features of head h for rows ib..ib+63
  float pl[4] = {}, pr[4] = {};
#pragma unroll
  for (int q = 0; q < 4; ++q)
#pragma unroll
    for (int c = 0; c < 4; ++c) {
      const int fl = tx * 4 + c;
      pl[q] = fmaf(acc[q][c], AL[col0 + fl], pl[q]);
      pr[q] = fmaf(acc[q][c], AR[col0 + fl], pr[q]);
    }
#pragma unroll
  for (int s = 1; s < 16; s <<= 1) {
#pragma unroll
    for (int q = 0; q < 4; ++q) { pl[q] += __shfl_xor(pl[q], s); pr[q] += __shfl_xor(pr[q], s); }
  }
  if (tx == 0) {
#pragma unroll
    for (int q = 0; q < 4; ++q) {
      ELt[(size_t)bh * N_ + ib + ty * 4 + q] = pl[q];
      ERt[(size_t)bh * N_ + ib + ty * 4 + q] = pr[q];
    }
  }
  // transposed bf16 store: HbT[bh][f][j]; acc[q][c] -> f = tx*4+c, j = ib + ty*4 + q
#pragma unroll
  for (int c = 0; c < 4; ++c) {
    ushort4 o;
    o.x = f2bf(acc[0][c]); o.y = f2bf(acc[1][c]); o.z = f2bf(acc[2][c]); o.w = f2bf(acc[3][c]);
    *(ushort4*)&HbT[(size_t)bh * (64 * N_) + (size_t)(tx * 4 + c) * N_ + ib + ty * 4] = o;
  }
}

// ---------------- Kernel B: adj -> packed neighbor bitmask (pure streaming) ----------------
// Thread covers 16 consecutive j (64B of adj), emits 16 mask bits as one ushort.
// Little-endian layout is bit-identical to the previous ballot-packed u64 array.
__global__ __launch_bounds__(256) void k_mask(const float* __restrict__ ADJ,
                                              unsigned short* __restrict__ MASK16) {
  const int idx = blockIdx.x * 256 + threadIdx.x;   // 0 .. B*N*64-1
  const float4* a = (const float4*)(ADJ + (size_t)idx * 16);
  unsigned int m = 0;
#pragma unroll
  for (int c = 0; c < 4; ++c) {
    const float4 v = a[c];
    m |= (v.x > 0.5f ? 1u : 0u) << (c * 4 + 0);
    m |= (v.y > 0.5f ? 1u : 0u) << (c * 4 + 1);
    m |= (v.z > 0.5f ? 1u : 0u) << (c * 4 + 2);
    m |= (v.w > 0.5f ? 1u : 0u) << (c * 4 + 3);
  }
  MASK16[idx] = (unsigned short)m;
}

// ---------------- Kernel B2: per-(b,h) global max of er (softmax stabilizer bound) ----------
__global__ __launch_bounds__(256) void k_ermax(const float* __restrict__ ERt,
                                               float* __restrict__ ERMAX) {
  __shared__ float red[4];
  const int bh = blockIdx.x, t = threadIdx.x, lane = t & 63, w = t >> 6;
  const float4 v = *(const float4*)&ERt[(size_t)bh * N_ + t * 4];
  float mx = fmaxf(fmaxf(v.x, v.y), fmaxf(v.z, v.w));
#pragma unroll
  for (int s = 32; s > 0; s >>= 1) mx = fmaxf(mx, __shfl_xor(mx, s));
  if (lane == 0) red[w] = mx;
  __syncthreads();
  if (t == 0) ERMAX[bh] = fmaxf(fmaxf(red[0], red[1]), fmaxf(red[2], red[3]));
}

// ---------------- Kernel C: MFMA aggregation (flash-attn PV style), no LDS ----------------
// Block: (b, h, 128-row i-tile), 4 waves; wave owns 32 i-rows x 64 f.
// A-frag (p) computed in registers in MFMA layout: row = lane&15, k = (lane>>4)*8 + e.
// B-frag (h) read as contiguous bf16x8 from HbT[bh][f][j]. Unnormalized accumulate; /= sum(p).
// Stabilizer: m = lrelu(el_i + max_j er_j) >= masked max (lrelu monotone); p in (0,1].
__global__ __launch_bounds__(256) void k_agg(const unsigned short* __restrict__ HbT,
                                             const float* __restrict__ ERt,
                                             const float* __restrict__ ELt,
                                             const float* __restrict__ ERMAX,
                                             const unsigned long long* __restrict__ MASK,
                                             const float* __restrict__ X,
                                             const float* __restrict__ BIAS,
                                             float* __restrict__ OUT) {
  const int t = threadIdx.x;
  const int lane = t & 63, w = t >> 6;
  const int bid = blockIdx.x;
  const int b = bid & 31;            // same b -> same XCD residency for its panel
  const int h = (bid >> 5) & 3;
  const int it = bid >> 7;           // 0..7
  const int bh = b * 4 + h;
  const int i0 = it * 128 + w * 32;
  const int r = lane & 15, kg = lane >> 4;
  const int iA0 = i0 + r;
  const int iA1 = i0 + 16 + r;

  const float ermax = ERMAX[bh];
  const float el0 = ELt[(size_t)bh * N_ + iA0];
  const float el1 = ELt[(size_t)bh * N_ + iA1];
  const float m0 = lrelu(el0 + ermax);
  const float m1 = lrelu(el1 + ermax);
  const unsigned long long* mrow0 = MASK + (size_t)(b * N_ + iA0) * 16;
  const unsigned long long* mrow1 = MASK + (size_t)(b * N_ + iA1) * 16;
  const unsigned short* hp = HbT + (size_t)bh * (64 * N_);
  const float* erp = ERt + (size_t)bh * N_;

  const f32x4 zero4 = {0.f, 0.f, 0.f, 0.f};
  f32x4 acc0[4], acc1[4];
#pragma unroll
  for (int c = 0; c < 4; ++c) { acc0[c] = zero4; acc1[c] = zero4; }
  float ps0 = 0.f, ps1 = 0.f;

  for (int j64 = 0; j64 < N_; j64 += 64) {
    const unsigned long long mw0 = mrow0[j64 >> 6];
    const unsigned long long mw1 = mrow1[j64 >> 6];
#pragma unroll
    for (int half = 0; half < 2; ++half) {
      const int jb = j64 + half * 32 + kg * 8;
      const int sh = half * 32 + kg * 8;
      const unsigned int bits0 = (unsigned int)(mw0 >> sh) & 0xffu;
      const unsigned int bits1 = (unsigned int)(mw1 >> sh) & 0xffu;
      const float4 ea = *(const float4*)&erp[jb];
      const float4 eb = *(const float4*)&erp[jb + 4];
      const float er8[8] = {ea.x, ea.y, ea.z, ea.w, eb.x, eb.y, eb.z, eb.w};
      union { bf16x8 v; unsigned short s[8]; } a0, a1;
#pragma unroll
      for (int e = 0; e < 8; ++e) {
        float z0 = el0 + er8[e];
        z0 = z0 > 0.f ? z0 : 0.2f * z0;
        z0 = ((bits0 >> e) & 1u) ? z0 : -1e9f;
        const float p0 = __expf(z0 - m0);
        ps0 += p0; a0.s[e] = f2bf(p0);
        float z1 = el1 + er8[e];
        z1 = z1 > 0.f ? z1 : 0.2f * z1;
        z1 = ((bits1 >> e) & 1u) ? z1 : -1e9f;
        const float p1 = __expf(z1 - m1);
        ps1 += p1; a1.s[e] = f2bf(p1);
      }
#pragma unroll
      for (int c = 0; c < 4; ++c) {
        const bf16x8 bv = *(const bf16x8*)&hp[(size_t)(c * 16 + r) * N_ + jb];
        acc0[c] = __builtin_amdgcn_mfma_f32_16x16x32_bf16(a0.v, bv, acc0[c], 0, 0, 0);
        acc1[c] = __builtin_amdgcn_mfma_f32_16x16x32_bf16(a1.v, bv, acc1[c], 0, 0, 0);
      }
    }
  }
  ps0 += __shfl_xor(ps0, 16); ps0 += __shfl_xor(ps0, 32);
  ps1 += __shfl_xor(ps1, 16); ps1 += __shfl_xor(ps1, 32);

  // epilogue: C/D layout col = lane&15, row = (lane>>4)*4 + reg (verified m89)
#pragma unroll
  for (int reg = 0; reg < 4; ++reg) {
    const int ir = kg * 4 + reg;
    const float d0 = __shfl(ps0, ir);   // lane ir holds psum for row i0+ir
    const float d1 = __shfl(ps1, ir);
    const int gi0 = b * N_ + i0 + ir;
    const int gi1 = gi0 + 16;
#pragma unroll
    for (int c = 0; c < 4; ++c) {
      const int f = h * 64 + c * 16 + r;
      const size_t off0 = (size_t)gi0 * OUTF_ + f;
      const size_t off1 = (size_t)gi1 * OUTF_ + f;
      float o0 = acc0[c][reg] / d0 + BIAS[f] + X[off0];
      o0 = o0 > 0.f ? o0 : __expf(o0) - 1.f;
      OUT[off0] = o0;
      float o1 = acc1[c][reg] / d1 + BIAS[f] + X[off1];
      o1 = o1 > 0.f ? o1 : __expf(o1) - 1.f;
      OUT[off1] = o1;
    }
  }
}

extern "C" void kernel_launch(void* const* d_in, const int* in_sizes, int n_in,
                              void* d_out, int out_size, void* d_ws, size_t ws_size,
                              hipStream_t stream) {
  const float* ADJ  = (const float*)d_in[0];
  const float* X    = (const float*)d_in[1];
  const float* W    = (const float*)d_in[2];
  const float* AL   = (const float*)d_in[3];
  const float* AR   = (const float*)d_in[4];
  const float* BIAS = (const float*)d_in[5];
  float* OUT = (float*)d_out;

  char* ws = (char*)d_ws;
  unsigned short* HbT = (unsigned short*)ws;                       // 16 MiB bf16 [128][64][1024]
  size_t off = (size_t)B_ * 4 * 64 * N_ * sizeof(unsigned short);
  float* ELt = (float*)(ws + off); off += (size_t)B_ * 4 * N_ * sizeof(float);
  float* ERt = (float*)(ws + off); off += (size_t)B_ * 4 * N_ * sizeof(float);
  float* ERMAX = (float*)(ws + off); off += 128 * sizeof(float);
  off = (off + 255) & ~(size_t)255;
  unsigned short* MASK16 = (unsigned short*)(ws + off);            // 4 MiB

  k_mask<<<8192, 256, 0, stream>>>(ADJ, MASK16);
  k_gemm_h<<<dim3(4, 512), 256, 0, stream>>>(X, W, AL, AR, HbT, ELt, ERt);
  k_ermax<<<128, 256, 0, stream>>>(ERt, ERMAX);
  k_agg<<<1024, 256, 0, stream>>>(HbT, ERt, ELt, ERMAX,
                                  (const unsigned long long*)MASK16, X, BIAS, OUT);
}

// Round 4
// 169.879 us; speedup vs baseline: 7.0739x; 1.1181x over previous
//
#include <hip/hip_runtime.h>
#include <hip/hip_fp16.h>
#include <stdint.h>

#define B_    32
#define N_    1024
#define K_    256
#define OUTF_ 256

typedef __attribute__((ext_vector_type(4))) float f32x4;
typedef __attribute__((ext_vector_type(8))) _Float16 f16x8;

__device__ __forceinline__ float lrelu(float z) { return z > 0.f ? z : 0.2f * z; }

__device__ __forceinline__ unsigned int pk2(float x) {
  unsigned int u = (unsigned int)__half_as_ushort(__float2half(x));
  return u | (u << 16);
}
__device__ __forceinline__ unsigned int pkadd(unsigned int a, unsigned int b) {
  union { unsigned int u; __half2 h; } A, Bv, R;
  A.u = a; Bv.u = b; R.h = __hadd2(A.h, Bv.h); return R.u;
}
__device__ __forceinline__ unsigned int pkmul(unsigned int a, unsigned int b) {
  union { unsigned int u; __half2 h; } A, Bv, R;
  A.u = a; Bv.u = b; R.h = __hmul2(A.h, Bv.h); return R.u;
}

// ---------------- prep: W[k][f] f32 -> WT[f][k] f16 ----------------
__global__ __launch_bounds__(256) void k_wt(const float* __restrict__ W,
                                            _Float16* __restrict__ WT) {
  const int k = blockIdx.x, f = threadIdx.x;
  WT[(size_t)f * K_ + k] = (_Float16)W[(size_t)k * OUTF_ + f];
}

// ---------------- adj -> packed neighbor bitmask (pure streaming) ----------------
__global__ __launch_bounds__(256) void k_mask(const float* __restrict__ ADJ,
                                              unsigned short* __restrict__ MASK16) {
  const int idx = blockIdx.x * 256 + threadIdx.x;   // 0 .. B*N*64-1
  const float4* a = (const float4*)(ADJ + (size_t)idx * 16);
  unsigned int m = 0;
#pragma unroll
  for (int c = 0; c < 4; ++c) {
    const float4 v = a[c];
    m |= (v.x > 0.5f ? 1u : 0u) << (c * 4 + 0);
    m |= (v.y > 0.5f ? 1u : 0u) << (c * 4 + 1);
    m |= (v.z > 0.5f ? 1u : 0u) << (c * 4 + 2);
    m |= (v.w > 0.5f ? 1u : 0u) << (c * 4 + 3);
  }
  MASK16[idx] = (unsigned short)m;
}

// ---------------- MFMA f16 GEMM: H = X @ W -> HbT[bh][f=64][j=N] f16 (transposed),
// fused el/er -> ELt/ERt f32, and u=e^er, v=e^{0.2 er}, erh f16. ----------------
__global__ __launch_bounds__(256) void k_gemm_h(
    const float* __restrict__ X, const _Float16* __restrict__ WT,
    const float* __restrict__ AL, const float* __restrict__ AR,
    _Float16* __restrict__ HbT, float* __restrict__ ELt, float* __restrict__ ERt,
    _Float16* __restrict__ UH, _Float16* __restrict__ VH, _Float16* __restrict__ ERH) {
  const int t = threadIdx.x, lane = t & 63, w = t >> 6;
  const int r = lane & 15, kg = lane >> 4;
  const int i0 = blockIdx.x * 64 + w * 16;   // 64-row tiles never cross a batch
  const int b = i0 >> 10;
  const int ib = i0 & (N_ - 1);

  f32x4 acc[16];
#pragma unroll
  for (int c = 0; c < 16; ++c) acc[c] = (f32x4){0.f, 0.f, 0.f, 0.f};

  const float* xrow = X + (size_t)(i0 + r) * K_;
#pragma unroll
  for (int ks = 0; ks < 8; ++ks) {
    const int k0 = ks * 32 + kg * 8;
    const float4 xa = *(const float4*)&xrow[k0];
    const float4 xb = *(const float4*)&xrow[k0 + 4];
    f16x8 a;
    a[0] = (_Float16)xa.x; a[1] = (_Float16)xa.y; a[2] = (_Float16)xa.z; a[3] = (_Float16)xa.w;
    a[4] = (_Float16)xb.x; a[5] = (_Float16)xb.y; a[6] = (_Float16)xb.z; a[7] = (_Float16)xb.w;
#pragma unroll
    for (int c = 0; c < 16; ++c) {
      const f16x8 bv = *(const f16x8*)&WT[(size_t)(c * 16 + r) * K_ + k0];
      acc[c] = __builtin_amdgcn_mfma_f32_16x16x32_f16(a, bv, acc[c], 0, 0, 0);
    }
  }
  // fused el/er: D col (=lane&15) is f within c-block; AL index = c*16+r (heads contiguous)
  float el[4][4] = {}, er[4][4] = {};
#pragma unroll
  for (int c = 0; c < 16; ++c) {
    const float al = AL[c * 16 + r], ar = AR[c * 16 + r];
    const int hh = c >> 2;
#pragma unroll
    for (int reg = 0; reg < 4; ++reg) {
      el[hh][reg] = fmaf(acc[c][reg], al, el[hh][reg]);
      er[hh][reg] = fmaf(acc[c][reg], ar, er[hh][reg]);
    }
  }
#pragma unroll
  for (int s = 1; s < 16; s <<= 1) {
#pragma unroll
    for (int hh = 0; hh < 4; ++hh)
#pragma unroll
      for (int reg = 0; reg < 4; ++reg) {
        el[hh][reg] += __shfl_xor(el[hh][reg], s);
        er[hh][reg] += __shfl_xor(er[hh][reg], s);
      }
  }
  if (r == 0) {
#pragma unroll
    for (int hh = 0; hh < 4; ++hh) {
      const int bh = b * 4 + hh;
#pragma unroll
      for (int reg = 0; reg < 4; ++reg) {
        const int ii = ib + kg * 4 + reg;
        const float e_l = el[hh][reg], e_r = er[hh][reg];
        ELt[(size_t)bh * N_ + ii] = e_l;
        ERt[(size_t)bh * N_ + ii] = e_r;
        UH[(size_t)bh * N_ + ii]  = (_Float16)__expf(e_r);
        VH[(size_t)bh * N_ + ii]  = (_Float16)__expf(0.2f * e_r);
        ERH[(size_t)bh * N_ + ii] = (_Float16)e_r;
      }
    }
  }
  // transposed f16 store: rows kg*4+reg are 4 consecutive j at fixed f
#pragma unroll
  for (int c = 0; c < 16; ++c) {
    const int bh = b * 4 + (c >> 2);
    const int fin = (c & 3) * 16 + r;
    union { _Float16 h[4]; ushort4 u; } pk;
#pragma unroll
    for (int reg = 0; reg < 4; ++reg) pk.h[reg] = (_Float16)acc[c][reg];
    *(ushort4*)&HbT[(size_t)bh * (64 * N_) + (size_t)fin * N_ + ib + kg * 4] = pk.u;
  }
}

// ---------------- per-(b,h) global er max ----------------
__global__ __launch_bounds__(256) void k_ermax(const float* __restrict__ ERt,
                                               float* __restrict__ ERMAX) {
  __shared__ float red[4];
  const int bh = blockIdx.x, t = threadIdx.x, lane = t & 63, w = t >> 6;
  const float4 v = *(const float4*)&ERt[(size_t)bh * N_ + t * 4];
  float mx = fmaxf(fmaxf(v.x, v.y), fmaxf(v.z, v.w));
#pragma unroll
  for (int s = 32; s > 0; s >>= 1) mx = fmaxf(mx, __shfl_xor(mx, s));
  if (lane == 0) red[w] = mx;
  __syncthreads();
  if (t == 0) ERMAX[bh] = fmaxf(fmaxf(red[0], red[1]), fmaxf(red[2], red[3]));
}

// ---------------- per-row A = e^{el-m}, C = e^{0.2 el-m}, m = lrelu(el+ermax) ----------------
__global__ __launch_bounds__(256) void k_prep(const float* __restrict__ ELt,
                                              const float* __restrict__ ERMAX,
                                              float2* __restrict__ ACb) {
  const int idx = blockIdx.x * 256 + threadIdx.x;   // 0..131071
  const int bh = idx >> 10;
  const float el = ELt[idx];
  const float m = lrelu(el + ERMAX[bh]);
  ACb[idx] = make_float2(__expf(el - m), __expf(0.2f * el - m));
}

// ---------------- MFMA aggregation, exp-free regime-split p generation ----------------
// p_ij = mask * (z>0 ? A_i*u_j : C_i*v_j), z = el_i + er_j (sign in packed f16).
// Fragments f16; psum via extra ones-B MFMA (row-sum in accumulator).
__global__ __launch_bounds__(256) void k_agg(
    const _Float16* __restrict__ HbT, const _Float16* __restrict__ UH,
    const _Float16* __restrict__ VH, const _Float16* __restrict__ ERH,
    const float* __restrict__ ELt, const float2* __restrict__ ACb,
    const unsigned long long* __restrict__ MASK,
    const float* __restrict__ X, const float* __restrict__ BIAS,
    float* __restrict__ OUT) {
  const int t = threadIdx.x, lane = t & 63, w = t >> 6;
  const int bid = blockIdx.x;
  const int b = bid & 31, h = (bid >> 5) & 3, it = bid >> 7;
  const int bh = b * 4 + h;
  const int i0 = it * 128 + w * 32;
  const int r = lane & 15, kg = lane >> 4;
  const int iA0 = i0 + r, iA1 = i0 + 16 + r;

  const float2 ac0 = ACb[(size_t)bh * N_ + iA0];
  const float2 ac1 = ACb[(size_t)bh * N_ + iA1];
  const unsigned int Apk0 = pk2(ac0.x), Cpk0 = pk2(ac0.y);
  const unsigned int Apk1 = pk2(ac1.x), Cpk1 = pk2(ac1.y);
  const unsigned int elpk0 = pk2(ELt[(size_t)bh * N_ + iA0]);
  const unsigned int elpk1 = pk2(ELt[(size_t)bh * N_ + iA1]);
  const unsigned long long* mrow0 = MASK + (size_t)(b * N_ + iA0) * 16;
  const unsigned long long* mrow1 = MASK + (size_t)(b * N_ + iA1) * 16;
  const _Float16* hp  = HbT + (size_t)bh * (64 * N_);
  const _Float16* up  = UH + (size_t)bh * N_;
  const _Float16* vp  = VH + (size_t)bh * N_;
  const _Float16* erp = ERH + (size_t)bh * N_;

  f16x8 onesv;
#pragma unroll
  for (int e = 0; e < 8; ++e) onesv[e] = (_Float16)1.0f;

  const f32x4 zero4 = {0.f, 0.f, 0.f, 0.f};
  f32x4 af0[4], af1[4], as0 = zero4, as1 = zero4;
#pragma unroll
  for (int c = 0; c < 4; ++c) { af0[c] = zero4; af1[c] = zero4; }

  for (int j64 = 0; j64 < N_; j64 += 64) {
    const unsigned long long mw0 = mrow0[j64 >> 6];
    const unsigned long long mw1 = mrow1[j64 >> 6];
#pragma unroll
    for (int half = 0; half < 2; ++half) {
      const int jb = j64 + half * 32 + kg * 8;
      const uint4 u4 = *(const uint4*)&up[jb];
      const uint4 v4 = *(const uint4*)&vp[jb];
      const uint4 e4 = *(const uint4*)&erp[jb];
      const int sh = half * 32 + kg * 8;
      const unsigned int bits0 = (unsigned int)(mw0 >> sh) & 0xffu;
      const unsigned int bits1 = (unsigned int)(mw1 >> sh) & 0xffu;
      union { unsigned int u[4]; f16x8 v; } a0, a1;
#pragma unroll
      for (int pp = 0; pp < 4; ++pp) {
        const unsigned int ep = ((const unsigned int*)&e4)[pp];
        const unsigned int uu = ((const unsigned int*)&u4)[pp];
        const unsigned int vv = ((const unsigned int*)&v4)[pp];
        // mask-pair expansion: bit e -> 0xFFFF in its half
        const unsigned int ml0 = (unsigned int)((int)(bits0 << (31 - 2 * pp)) >> 31);
        const unsigned int mh0 = (unsigned int)((int)(bits0 << (30 - 2 * pp)) >> 31);
        const unsigned int mp0 = (mh0 & 0xFFFF0000u) | (ml0 & 0xFFFFu);
        const unsigned int ml1 = (unsigned int)((int)(bits1 << (31 - 2 * pp)) >> 31);
        const unsigned int mh1 = (unsigned int)((int)(bits1 << (30 - 2 * pp)) >> 31);
        const unsigned int mp1 = (mh1 & 0xFFFF0000u) | (ml1 & 0xFFFFu);
        // sign of z per half
        const unsigned int zz0 = pkadd(elpk0, ep);
        const unsigned int sgl0 = (unsigned int)((int)(zz0 << 16) >> 31);
        const unsigned int sgh0 = (unsigned int)((int)zz0 >> 31);
        const unsigned int sg0 = (sgh0 & 0xFFFF0000u) | (sgl0 & 0xFFFFu);
        const unsigned int zz1 = pkadd(elpk1, ep);
        const unsigned int sgl1 = (unsigned int)((int)(zz1 << 16) >> 31);
        const unsigned int sgh1 = (unsigned int)((int)zz1 >> 31);
        const unsigned int sg1 = (sgh1 & 0xFFFF0000u) | (sgl1 & 0xFFFFu);
        // candidate products, bitwise select
        const unsigned int pu0 = pkmul(Apk0, uu), pv0 = pkmul(Cpk0, vv);
        const unsigned int pu1 = pkmul(Apk1, uu), pv1 = pkmul(Cpk1, vv);
        a0.u[pp] = (pu0 & (mp0 & ~sg0)) | (pv0 & (mp0 & sg0));
        a1.u[pp] = (pu1 & (mp1 & ~sg1)) | (pv1 & (mp1 & sg1));
      }
#pragma unroll
      for (int c = 0; c < 4; ++c) {
        const f16x8 bv = *(const f16x8*)&hp[(size_t)(c * 16 + r) * N_ + jb];
        af0[c] = __builtin_amdgcn_mfma_f32_16x16x32_f16(a0.v, bv, af0[c], 0, 0, 0);
        af1[c] = __builtin_amdgcn_mfma_f32_16x16x32_f16(a1.v, bv, af1[c], 0, 0, 0);
      }
      as0 = __builtin_amdgcn_mfma_f32_16x16x32_f16(a0.v, onesv, as0, 0, 0, 0);
      as1 = __builtin_amdgcn_mfma_f32_16x16x32_f16(a1.v, onesv, as1, 0, 0, 0);
    }
  }

  // epilogue: D row = kg*4+reg, col = r; psum = ones-acc (all cols equal)
#pragma unroll
  for (int reg = 0; reg < 4; ++reg) {
    const int ir0 = i0 + kg * 4 + reg;
    const int ir1 = ir0 + 16;
    const float inv0 = 1.0f / as0[reg];
    const float inv1 = 1.0f / as1[reg];
#pragma unroll
    for (int c = 0; c < 4; ++c) {
      const int f = h * 64 + c * 16 + r;
      const size_t off0 = (size_t)(b * N_ + ir0) * OUTF_ + f;
      const size_t off1 = (size_t)(b * N_ + ir1) * OUTF_ + f;
      float o0 = af0[c][reg] * inv0 + BIAS[f] + X[off0];
      o0 = o0 > 0.f ? o0 : __expf(o0) - 1.f;
      OUT[off0] = o0;
      float o1 = af1[c][reg] * inv1 + BIAS[f] + X[off1];
      o1 = o1 > 0.f ? o1 : __expf(o1) - 1.f;
      OUT[off1] = o1;
    }
  }
}

extern "C" void kernel_launch(void* const* d_in, const int* in_sizes, int n_in,
                              void* d_out, int out_size, void* d_ws, size_t ws_size,
                              hipStream_t stream) {
  const float* ADJ  = (const float*)d_in[0];
  const float* X    = (const float*)d_in[1];
  const float* W    = (const float*)d_in[2];
  const float* AL   = (const float*)d_in[3];
  const float* AR   = (const float*)d_in[4];
  const float* BIAS = (const float*)d_in[5];
  float* OUT = (float*)d_out;

  char* ws = (char*)d_ws;
  size_t off = 0;
  _Float16* HbT = (_Float16*)(ws + off); off += (size_t)B_ * 4 * 64 * N_ * 2;      // 16 MiB
  _Float16* WT  = (_Float16*)(ws + off); off += (size_t)K_ * OUTF_ * 2;            // 128 KiB
  float* ELt    = (float*)(ws + off);    off += (size_t)B_ * 4 * N_ * 4;           // 512 KiB
  float* ERt    = (float*)(ws + off);    off += (size_t)B_ * 4 * N_ * 4;           // 512 KiB
  _Float16* UH  = (_Float16*)(ws + off); off += (size_t)B_ * 4 * N_ * 2;           // 256 KiB
  _Float16* VH  = (_Float16*)(ws + off); off += (size_t)B_ * 4 * N_ * 2;
  _Float16* ERH = (_Float16*)(ws + off); off += (size_t)B_ * 4 * N_ * 2;
  float* ERMAX  = (float*)(ws + off);    off += 512;
  float2* ACb   = (float2*)(ws + off);   off += (size_t)B_ * 4 * N_ * 8;           // 1 MiB
  unsigned short* MASK16 = (unsigned short*)(ws + off);                             // 4 MiB

  k_wt<<<256, 256, 0, stream>>>(W, WT);
  k_mask<<<8192, 256, 0, stream>>>(ADJ, MASK16);
  k_gemm_h<<<512, 256, 0, stream>>>(X, WT, AL, AR, HbT, ELt, ERt, UH, VH, ERH);
  k_ermax<<<128, 256, 0, stream>>>(ERt, ERMAX);
  k_prep<<<512, 256, 0, stream>>>(ELt, ERMAX, ACb);
  k_agg<<<1024, 256, 0, stream>>>(HbT, UH, VH, ERH, ELt, ACb,
                                  (const unsigned long long*)MASK16, X, BIAS, OUT);
}

// Round 5
// 135.764 us; speedup vs baseline: 8.8515x; 1.2513x over previous
//
#include <hip/hip_runtime.h>
#include <hip/hip_fp16.h>
#include <stdint.h>

#define B_    32
#define N_    1024
#define K_    256
#define OUTF_ 256

typedef __attribute__((ext_vector_type(4))) float f32x4;
typedef __attribute__((ext_vector_type(8))) _Float16 f16x8;

__device__ __forceinline__ float lrelu(float z) { return z > 0.f ? z : 0.2f * z; }

__device__ __forceinline__ unsigned int pk2(float x) {
  unsigned int u = (unsigned int)__half_as_ushort(__float2half(x));
  return u | (u << 16);
}
__device__ __forceinline__ unsigned int pkmul(unsigned int a, unsigned int b) {
  union { unsigned int u; __half2 h; } A, Bv, R;
  A.u = a; Bv.u = b; R.h = __hmul2(A.h, Bv.h); return R.u;
}
__device__ __forceinline__ unsigned int pkmax(unsigned int a, unsigned int b) {
  unsigned int r;
  asm("v_pk_max_f16 %0, %1, %2" : "=v"(r) : "v"(a), "v"(b));
  return r;
}

// ---------------- prep: W[k][f] f32 -> WT[f][k] f16 ----------------
__global__ __launch_bounds__(256) void k_wt(const float* __restrict__ W,
                                            _Float16* __restrict__ WT) {
  const int k = blockIdx.x, f = threadIdx.x;
  WT[(size_t)f * K_ + k] = (_Float16)W[(size_t)k * OUTF_ + f];
}

// ---------------- adj -> packed neighbor bitmask (pure streaming) ----------------
__global__ __launch_bounds__(256) void k_mask(const float* __restrict__ ADJ,
                                              unsigned short* __restrict__ MASK16) {
  const int idx = blockIdx.x * 256 + threadIdx.x;   // 0 .. B*N*64-1
  const float4* a = (const float4*)(ADJ + (size_t)idx * 16);
  unsigned int m = 0;
#pragma unroll
  for (int c = 0; c < 4; ++c) {
    const float4 v = a[c];
    m |= (v.x > 0.5f ? 1u : 0u) << (c * 4 + 0);
    m |= (v.y > 0.5f ? 1u : 0u) << (c * 4 + 1);
    m |= (v.z > 0.5f ? 1u : 0u) << (c * 4 + 2);
    m |= (v.w > 0.5f ? 1u : 0u) << (c * 4 + 3);
  }
  MASK16[idx] = (unsigned short)m;
}

// ---------------- MFMA f16 GEMM: H = X @ W -> HbT[bh][f=64][j=N] f16 (transposed),
// fused el/er -> ELt/ERt f32, and u=e^er, v=e^{0.2 er} f16. ----------------
__global__ __launch_bounds__(256) void k_gemm_h(
    const float* __restrict__ X, const _Float16* __restrict__ WT,
    const float* __restrict__ AL, const float* __restrict__ AR,
    _Float16* __restrict__ HbT, float* __restrict__ ELt, float* __restrict__ ERt,
    _Float16* __restrict__ UH, _Float16* __restrict__ VH) {
  const int t = threadIdx.x, lane = t & 63, w = t >> 6;
  const int r = lane & 15, kg = lane >> 4;
  const int i0 = blockIdx.x * 64 + w * 16;   // 64-row tiles never cross a batch
  const int b = i0 >> 10;
  const int ib = i0 & (N_ - 1);

  f32x4 acc[16];
#pragma unroll
  for (int c = 0; c < 16; ++c) acc[c] = (f32x4){0.f, 0.f, 0.f, 0.f};

  const float* xrow = X + (size_t)(i0 + r) * K_;
#pragma unroll
  for (int ks = 0; ks < 8; ++ks) {
    const int k0 = ks * 32 + kg * 8;
    const float4 xa = *(const float4*)&xrow[k0];
    const float4 xb = *(const float4*)&xrow[k0 + 4];
    f16x8 a;
    a[0] = (_Float16)xa.x; a[1] = (_Float16)xa.y; a[2] = (_Float16)xa.z; a[3] = (_Float16)xa.w;
    a[4] = (_Float16)xb.x; a[5] = (_Float16)xb.y; a[6] = (_Float16)xb.z; a[7] = (_Float16)xb.w;
#pragma unroll
    for (int c = 0; c < 16; ++c) {
      const f16x8 bv = *(const f16x8*)&WT[(size_t)(c * 16 + r) * K_ + k0];
      acc[c] = __builtin_amdgcn_mfma_f32_16x16x32_f16(a, bv, acc[c], 0, 0, 0);
    }
  }
  // fused el/er
  float el[4][4] = {}, er[4][4] = {};
#pragma unroll
  for (int c = 0; c < 16; ++c) {
    const float al = AL[c * 16 + r], ar = AR[c * 16 + r];
    const int hh = c >> 2;
#pragma unroll
    for (int reg = 0; reg < 4; ++reg) {
      el[hh][reg] = fmaf(acc[c][reg], al, el[hh][reg]);
      er[hh][reg] = fmaf(acc[c][reg], ar, er[hh][reg]);
    }
  }
#pragma unroll
  for (int s = 1; s < 16; s <<= 1) {
#pragma unroll
    for (int hh = 0; hh < 4; ++hh)
#pragma unroll
      for (int reg = 0; reg < 4; ++reg) {
        el[hh][reg] += __shfl_xor(el[hh][reg], s);
        er[hh][reg] += __shfl_xor(er[hh][reg], s);
      }
  }
  if (r == 0) {
#pragma unroll
    for (int hh = 0; hh < 4; ++hh) {
      const int bh = b * 4 + hh;
#pragma unroll
      for (int reg = 0; reg < 4; ++reg) {
        const int ii = ib + kg * 4 + reg;
        const float e_l = el[hh][reg], e_r = er[hh][reg];
        ELt[(size_t)bh * N_ + ii] = e_l;
        ERt[(size_t)bh * N_ + ii] = e_r;
        UH[(size_t)bh * N_ + ii]  = (_Float16)__expf(e_r);
        VH[(size_t)bh * N_ + ii]  = (_Float16)__expf(0.2f * e_r);
      }
    }
  }
  // transposed f16 store
#pragma unroll
  for (int c = 0; c < 16; ++c) {
    const int bh = b * 4 + (c >> 2);
    const int fin = (c & 3) * 16 + r;
    union { _Float16 h[4]; ushort4 u; } pk;
#pragma unroll
    for (int reg = 0; reg < 4; ++reg) pk.h[reg] = (_Float16)acc[c][reg];
    *(ushort4*)&HbT[(size_t)bh * (64 * N_) + (size_t)fin * N_ + ib + kg * 4] = pk.u;
  }
}

// ---------------- per-(b,h) global er max ----------------
__global__ __launch_bounds__(256) void k_ermax(const float* __restrict__ ERt,
                                               float* __restrict__ ERMAX) {
  __shared__ float red[4];
  const int bh = blockIdx.x, t = threadIdx.x, lane = t & 63, w = t >> 6;
  const float4 v = *(const float4*)&ERt[(size_t)bh * N_ + t * 4];
  float mx = fmaxf(fmaxf(v.x, v.y), fmaxf(v.z, v.w));
#pragma unroll
  for (int s = 32; s > 0; s >>= 1) mx = fmaxf(mx, __shfl_xor(mx, s));
  if (lane == 0) red[w] = mx;
  __syncthreads();
  if (t == 0) ERMAX[bh] = fmaxf(fmaxf(red[0], red[1]), fmaxf(red[2], red[3]));
}

// ---------------- per-row A = e^{el-m}, C = e^{0.2 el-m}, m = lrelu(el+ermax) ----------------
__global__ __launch_bounds__(256) void k_prep(const float* __restrict__ ELt,
                                              const float* __restrict__ ERMAX,
                                              float2* __restrict__ ACb) {
  const int idx = blockIdx.x * 256 + threadIdx.x;   // 0..131071
  const int bh = idx >> 10;
  const float el = ELt[idx];
  const float m = lrelu(el + ERMAX[bh]);
  ACb[idx] = make_float2(__expf(el - m), __expf(0.2f * el - m));
}

// ---------------- MFMA aggregation, exp-free, max-trick p generation ----------------
// lrelu(z) = max(z, 0.2z); exp monotone => p = mask ? max(A_i*u_j, C_i*v_j) : 0.
// Wave = 64 i-rows (4 MFMA row-groups) x 64 f; B-fragments reused by 4 groups.
__global__ __launch_bounds__(256, 2) void k_agg(
    const _Float16* __restrict__ HbT, const _Float16* __restrict__ UH,
    const _Float16* __restrict__ VH, const float2* __restrict__ ACb,
    const unsigned long long* __restrict__ MASK,
    const float* __restrict__ X, const float* __restrict__ BIAS,
    float* __restrict__ OUT) {
  const int t = threadIdx.x, lane = t & 63, w = t >> 6;
  const int bid = blockIdx.x;
  const int b = bid & 31, h = (bid >> 5) & 3, it = bid >> 7;  // it in 0..3
  const int bh = b * 4 + h;
  const int i0 = it * 256 + w * 64;
  const int r = lane & 15, kg = lane >> 4;

  unsigned int Apk[4], Cpk[4];
  const unsigned long long* mrow[4];
#pragma unroll
  for (int g = 0; g < 4; ++g) {
    const int ig = i0 + g * 16 + r;
    const float2 ac = ACb[(size_t)bh * N_ + ig];
    Apk[g] = pk2(ac.x); Cpk[g] = pk2(ac.y);
    mrow[g] = MASK + (size_t)(b * N_ + ig) * 16;
  }
  const _Float16* hp = HbT + (size_t)bh * (64 * N_);
  const _Float16* up = UH + (size_t)bh * N_;
  const _Float16* vp = VH + (size_t)bh * N_;

  f16x8 onesv;
#pragma unroll
  for (int e = 0; e < 8; ++e) onesv[e] = (_Float16)1.0f;

  const f32x4 zero4 = {0.f, 0.f, 0.f, 0.f};
  f32x4 af[4][4], as_[4];
#pragma unroll
  for (int g = 0; g < 4; ++g) {
    as_[g] = zero4;
#pragma unroll
    for (int c = 0; c < 4; ++c) af[g][c] = zero4;
  }

  for (int j64 = 0; j64 < N_; j64 += 64) {
    // issue ALL of this iteration's loads up front
    unsigned long long mw[4];
#pragma unroll
    for (int g = 0; g < 4; ++g) mw[g] = mrow[g][j64 >> 6];
    const int jlo = j64 + kg * 8, jhi = j64 + 32 + kg * 8;
    const uint4 ulo = *(const uint4*)&up[jlo];
    const uint4 uhi = *(const uint4*)&up[jhi];
    const uint4 vlo = *(const uint4*)&vp[jlo];
    const uint4 vhi = *(const uint4*)&vp[jhi];
    f16x8 bv[2][4];
#pragma unroll
    for (int half = 0; half < 2; ++half)
#pragma unroll
      for (int c = 0; c < 4; ++c)
        bv[half][c] = *(const f16x8*)&hp[(size_t)(c * 16 + r) * N_ + j64 + half * 32 + kg * 8];

#pragma unroll
    for (int half = 0; half < 2; ++half) {
      const uint4& uu4 = half ? uhi : ulo;
      const uint4& vv4 = half ? vhi : vlo;
#pragma unroll
      for (int g = 0; g < 4; ++g) {
        const unsigned int mword = (unsigned int)(mw[g] >> (half * 32));
        const unsigned int bits = (mword >> (kg * 8)) & 0xffu;
        union { unsigned int u[4]; f16x8 v; } a;
#pragma unroll
        for (int pp = 0; pp < 4; ++pp) {
          const unsigned int ml = (unsigned int)((int)(bits << (31 - 2 * pp)) >> 31);
          const unsigned int mh = (unsigned int)((int)(bits << (30 - 2 * pp)) >> 31);
          const unsigned int mp = (mh & 0xFFFF0000u) | (ml & 0xFFFFu);
          const unsigned int pu = pkmul(Apk[g], ((const unsigned int*)&uu4)[pp]);
          const unsigned int pv = pkmul(Cpk[g], ((const unsigned int*)&vv4)[pp]);
          a.u[pp] = pkmax(pu, pv) & mp;
        }
#pragma unroll
        for (int c = 0; c < 4; ++c)
          af[g][c] = __builtin_amdgcn_mfma_f32_16x16x32_f16(a.v, bv[half][c], af[g][c], 0, 0, 0);
        as_[g] = __builtin_amdgcn_mfma_f32_16x16x32_f16(a.v, onesv, as_[g], 0, 0, 0);
      }
    }
  }

  // epilogue: D row = kg*4+reg (i within group), col = r (f within c-block)
  float bias_c[4];
#pragma unroll
  for (int c = 0; c < 4; ++c) bias_c[c] = BIAS[h * 64 + c * 16 + r];
#pragma unroll
  for (int g = 0; g < 4; ++g) {
#pragma unroll
    for (int reg = 0; reg < 4; ++reg) {
      const int ir = i0 + g * 16 + kg * 4 + reg;
      const float inv = 1.0f / as_[g][reg];
#pragma unroll
      for (int c = 0; c < 4; ++c) {
        const int f = h * 64 + c * 16 + r;
        const size_t off = (size_t)(b * N_ + ir) * OUTF_ + f;
        float o = af[g][c][reg] * inv + bias_c[c] + X[off];
        o = o > 0.f ? o : __expf(o) - 1.f;
        OUT[off] = o;
      }
    }
  }
}

extern "C" void kernel_launch(void* const* d_in, const int* in_sizes, int n_in,
                              void* d_out, int out_size, void* d_ws, size_t ws_size,
                              hipStream_t stream) {
  const float* ADJ  = (const float*)d_in[0];
  const float* X    = (const float*)d_in[1];
  const float* W    = (const float*)d_in[2];
  const float* AL   = (const float*)d_in[3];
  const float* AR   = (const float*)d_in[4];
  const float* BIAS = (const float*)d_in[5];
  float* OUT = (float*)d_out;

  char* ws = (char*)d_ws;
  size_t off = 0;
  _Float16* HbT = (_Float16*)(ws + off); off += (size_t)B_ * 4 * 64 * N_ * 2;      // 16 MiB
  _Float16* WT  = (_Float16*)(ws + off); off += (size_t)K_ * OUTF_ * 2;            // 128 KiB
  float* ELt    = (float*)(ws + off);    off += (size_t)B_ * 4 * N_ * 4;           // 512 KiB
  float* ERt    = (float*)(ws + off);    off += (size_t)B_ * 4 * N_ * 4;           // 512 KiB
  _Float16* UH  = (_Float16*)(ws + off); off += (size_t)B_ * 4 * N_ * 2;           // 256 KiB
  _Float16* VH  = (_Float16*)(ws + off); off += (size_t)B_ * 4 * N_ * 2;
  float* ERMAX  = (float*)(ws + off);    off += 512;
  float2* ACb   = (float2*)(ws + off);   off += (size_t)B_ * 4 * N_ * 8;           // 1 MiB
  unsigned short* MASK16 = (unsigned short*)(ws + off);                             // 4 MiB

  k_wt<<<256, 256, 0, stream>>>(W, WT);
  k_mask<<<8192, 256, 0, stream>>>(ADJ, MASK16);
  k_gemm_h<<<512, 256, 0, stream>>>(X, WT, AL, AR, HbT, ELt, ERt, UH, VH);
  k_ermax<<<128, 256, 0, stream>>>(ERt, ERMAX);
  k_prep<<<512, 256, 0, stream>>>(ELt, ERMAX, ACb);
  k_agg<<<512, 256, 0, stream>>>(HbT, UH, VH, ACb,
                                 (const unsigned long long*)MASK16, X, BIAS, OUT);
}

// Round 6
// 131.061 us; speedup vs baseline: 9.1692x; 1.0359x over previous
//
#include <hip/hip_runtime.h>
#include <hip/hip_fp16.h>
#include <stdint.h>

#define B_    32
#define N_    1024
#define K_    256
#define OUTF_ 256

typedef __attribute__((ext_vector_type(4))) float f32x4;
typedef __attribute__((ext_vector_type(8))) _Float16 f16x8;

__device__ __forceinline__ float lrelu(float z) { return z > 0.f ? z : 0.2f * z; }

__device__ __forceinline__ unsigned int pk2(float x) {
  unsigned int u = (unsigned int)__half_as_ushort(__float2half(x));
  return u | (u << 16);
}
__device__ __forceinline__ unsigned int pkmul(unsigned int a, unsigned int b) {
  union { unsigned int u; __half2 h; } A, Bv, R;
  A.u = a; Bv.u = b; R.h = __hmul2(A.h, Bv.h); return R.u;
}
__device__ __forceinline__ unsigned int pkmax(unsigned int a, unsigned int b) {
  unsigned int r;
  asm("v_pk_max_f16 %0, %1, %2" : "=v"(r) : "v"(a), "v"(b));
  return r;
}

// ---------------- prep: W[k][f] f32 -> WT[f][k] f16 ----------------
__global__ __launch_bounds__(256) void k_wt(const float* __restrict__ W,
                                            _Float16* __restrict__ WT) {
  const int k = blockIdx.x, f = threadIdx.x;
  WT[(size_t)f * K_ + k] = (_Float16)W[(size_t)k * OUTF_ + f];
}

// ---------------- adj -> transposed bitmask MASKT[b][jw][i] (u64 of 64 j-bits) -------------
__global__ __launch_bounds__(256) void k_maskT(const float* __restrict__ ADJ,
                                               unsigned long long* __restrict__ MASKT) {
  const int t = threadIdx.x, lane = t & 63, w = t >> 6;
  const int row = blockIdx.x * 4 + w;          // b*N + i
  const int b = row >> 10, i = row & (N_ - 1);
  const float* arow = ADJ + (size_t)row * N_;
#pragma unroll
  for (int jw = 0; jw < 16; ++jw) {
    const unsigned long long bits = __ballot(arow[jw * 64 + lane] > 0.5f);
    if (lane == 0) MASKT[((size_t)b * 16 + jw) * N_ + i] = bits;
  }
}

// ---------------- MFMA f16 GEMM: H = X @ W -> HbT[bh][f=64][j=N] f16 (transposed),
// fused el/er -> ELt/ERt f32, and u=e^er, v=e^{0.2 er} f16. ----------------
__global__ __launch_bounds__(256) void k_gemm_h(
    const float* __restrict__ X, const _Float16* __restrict__ WT,
    const float* __restrict__ AL, const float* __restrict__ AR,
    _Float16* __restrict__ HbT, float* __restrict__ ELt, float* __restrict__ ERt,
    _Float16* __restrict__ UH, _Float16* __restrict__ VH) {
  const int t = threadIdx.x, lane = t & 63, w = t >> 6;
  const int r = lane & 15, kg = lane >> 4;
  const int i0 = blockIdx.x * 64 + w * 16;   // 64-row tiles never cross a batch
  const int b = i0 >> 10;
  const int ib = i0 & (N_ - 1);

  f32x4 acc[16];
#pragma unroll
  for (int c = 0; c < 16; ++c) acc[c] = (f32x4){0.f, 0.f, 0.f, 0.f};

  const float* xrow = X + (size_t)(i0 + r) * K_;
#pragma unroll
  for (int ks = 0; ks < 8; ++ks) {
    const int k0 = ks * 32 + kg * 8;
    const float4 xa = *(const float4*)&xrow[k0];
    const float4 xb = *(const float4*)&xrow[k0 + 4];
    f16x8 a;
    a[0] = (_Float16)xa.x; a[1] = (_Float16)xa.y; a[2] = (_Float16)xa.z; a[3] = (_Float16)xa.w;
    a[4] = (_Float16)xb.x; a[5] = (_Float16)xb.y; a[6] = (_Float16)xb.z; a[7] = (_Float16)xb.w;
#pragma unroll
    for (int c = 0; c < 16; ++c) {
      const f16x8 bv = *(const f16x8*)&WT[(size_t)(c * 16 + r) * K_ + k0];
      acc[c] = __builtin_amdgcn_mfma_f32_16x16x32_f16(a, bv, acc[c], 0, 0, 0);
    }
  }
  // fused el/er
  float el[4][4] = {}, er[4][4] = {};
#pragma unroll
  for (int c = 0; c < 16; ++c) {
    const float al = AL[c * 16 + r], ar = AR[c * 16 + r];
    const int hh = c >> 2;
#pragma unroll
    for (int reg = 0; reg < 4; ++reg) {
      el[hh][reg] = fmaf(acc[c][reg], al, el[hh][reg]);
      er[hh][reg] = fmaf(acc[c][reg], ar, er[hh][reg]);
    }
  }
#pragma unroll
  for (int s = 1; s < 16; s <<= 1) {
#pragma unroll
    for (int hh = 0; hh < 4; ++hh)
#pragma unroll
      for (int reg = 0; reg < 4; ++reg) {
        el[hh][reg] += __shfl_xor(el[hh][reg], s);
        er[hh][reg] += __shfl_xor(er[hh][reg], s);
      }
  }
  if (r == 0) {
#pragma unroll
    for (int hh = 0; hh < 4; ++hh) {
      const int bh = b * 4 + hh;
#pragma unroll
      for (int reg = 0; reg < 4; ++reg) {
        const int ii = ib + kg * 4 + reg;
        const float e_l = el[hh][reg], e_r = er[hh][reg];
        ELt[(size_t)bh * N_ + ii] = e_l;
        ERt[(size_t)bh * N_ + ii] = e_r;
        UH[(size_t)bh * N_ + ii]  = (_Float16)__expf(e_r);
        VH[(size_t)bh * N_ + ii]  = (_Float16)__expf(0.2f * e_r);
      }
    }
  }
  // transposed f16 store
#pragma unroll
  for (int c = 0; c < 16; ++c) {
    const int bh = b * 4 + (c >> 2);
    const int fin = (c & 3) * 16 + r;
    union { _Float16 h[4]; ushort4 u; } pk;
#pragma unroll
    for (int reg = 0; reg < 4; ++reg) pk.h[reg] = (_Float16)acc[c][reg];
    *(ushort4*)&HbT[(size_t)bh * (64 * N_) + (size_t)fin * N_ + ib + kg * 4] = pk.u;
  }
}

// ---------------- fused: per-(b,h) er max + per-row A=e^{el-m}, C=e^{0.2el-m} ----------------
__global__ __launch_bounds__(256) void k_acprep(const float* __restrict__ ERt,
                                                const float* __restrict__ ELt,
                                                float2* __restrict__ ACb) {
  __shared__ float red[4];
  const int bh = blockIdx.x, t = threadIdx.x, lane = t & 63, w = t >> 6;
  const float4 v = *(const float4*)&ERt[(size_t)bh * N_ + t * 4];
  float mx = fmaxf(fmaxf(v.x, v.y), fmaxf(v.z, v.w));
#pragma unroll
  for (int s = 32; s > 0; s >>= 1) mx = fmaxf(mx, __shfl_xor(mx, s));
  if (lane == 0) red[w] = mx;
  __syncthreads();
  const float ermax = fmaxf(fmaxf(red[0], red[1]), fmaxf(red[2], red[3]));
  const float4 el4 = *(const float4*)&ELt[(size_t)bh * N_ + t * 4];
  const float els[4] = {el4.x, el4.y, el4.z, el4.w};
#pragma unroll
  for (int q = 0; q < 4; ++q) {
    const float m = lrelu(els[q] + ermax);
    ACb[(size_t)bh * N_ + t * 4 + q] = make_float2(__expf(els[q] - m), __expf(0.2f * els[q] - m));
  }
}

// ---------------- MFMA aggregation, exp-free, max-trick, 2-deep pipelined ----------------
__device__ __forceinline__ void issue_loads(int j64, int i0, int r, int kg,
    const unsigned long long* __restrict__ mrowT, const _Float16* __restrict__ up,
    const _Float16* __restrict__ vp, const _Float16* __restrict__ hp,
    unsigned long long mw[4], uint4 uu[2], uint4 vv[2], f16x8 bv[2][4]) {
#pragma unroll
  for (int g = 0; g < 4; ++g) mw[g] = mrowT[(size_t)(j64 >> 6) * N_ + i0 + g * 16 + r];
  const int jl = j64 + kg * 8, jh = jl + 32;
  uu[0] = *(const uint4*)&up[jl]; uu[1] = *(const uint4*)&up[jh];
  vv[0] = *(const uint4*)&vp[jl]; vv[1] = *(const uint4*)&vp[jh];
#pragma unroll
  for (int half = 0; half < 2; ++half)
#pragma unroll
    for (int c = 0; c < 4; ++c)
      bv[half][c] = *(const f16x8*)&hp[(size_t)(c * 16 + r) * N_ + j64 + half * 32 + kg * 8];
}

__device__ __forceinline__ void compute_tile(const unsigned long long mw[4],
    const uint4 uu[2], const uint4 vv[2], const f16x8 bv[2][4],
    const unsigned int Apk[4], const unsigned int Cpk[4], int kg,
    f32x4 af[4][4], f32x4 as_[4], const f16x8& onesv) {
#pragma unroll
  for (int half = 0; half < 2; ++half) {
#pragma unroll
    for (int g = 0; g < 4; ++g) {
      const unsigned int bits = (unsigned int)(mw[g] >> (half * 32 + kg * 8)) & 0xffu;
      union { unsigned int u[4]; f16x8 v; } a;
#pragma unroll
      for (int pp = 0; pp < 4; ++pp) {
        const unsigned int ml = (unsigned int)((int)(bits << (31 - 2 * pp)) >> 31);
        const unsigned int mh = (unsigned int)((int)(bits << (30 - 2 * pp)) >> 31);
        const unsigned int mp = (mh & 0xFFFF0000u) | (ml & 0xFFFFu);
        const unsigned int pu = pkmul(Apk[g], ((const unsigned int*)&uu[half])[pp]);
        const unsigned int pv = pkmul(Cpk[g], ((const unsigned int*)&vv[half])[pp]);
        a.u[pp] = pkmax(pu, pv) & mp;
      }
#pragma unroll
      for (int c = 0; c < 4; ++c)
        af[g][c] = __builtin_amdgcn_mfma_f32_16x16x32_f16(a.v, bv[half][c], af[g][c], 0, 0, 0);
      as_[g] = __builtin_amdgcn_mfma_f32_16x16x32_f16(a.v, onesv, as_[g], 0, 0, 0);
    }
  }
}

__global__ __launch_bounds__(256, 2) void k_agg(
    const _Float16* __restrict__ HbT, const _Float16* __restrict__ UH,
    const _Float16* __restrict__ VH, const float2* __restrict__ ACb,
    const unsigned long long* __restrict__ MASKT,
    const float* __restrict__ X, const float* __restrict__ BIAS,
    float* __restrict__ OUT) {
  const int t = threadIdx.x, lane = t & 63, w = t >> 6;
  const int bid = blockIdx.x;
  const int b = bid & 31, h = (bid >> 5) & 3, it = bid >> 7;  // it in 0..3
  const int bh = b * 4 + h;
  const int i0 = it * 256 + w * 64;
  const int r = lane & 15, kg = lane >> 4;

  unsigned int Apk[4], Cpk[4];
#pragma unroll
  for (int g = 0; g < 4; ++g) {
    const float2 ac = ACb[(size_t)bh * N_ + i0 + g * 16 + r];
    Apk[g] = pk2(ac.x); Cpk[g] = pk2(ac.y);
  }
  const unsigned long long* mrowT = MASKT + (size_t)b * 16 * N_;
  const _Float16* hp = HbT + (size_t)bh * (64 * N_);
  const _Float16* up = UH + (size_t)bh * N_;
  const _Float16* vp = VH + (size_t)bh * N_;

  f16x8 onesv;
#pragma unroll
  for (int e = 0; e < 8; ++e) onesv[e] = (_Float16)1.0f;

  const f32x4 zero4 = {0.f, 0.f, 0.f, 0.f};
  f32x4 af[4][4], as_[4];
#pragma unroll
  for (int g = 0; g < 4; ++g) {
    as_[g] = zero4;
#pragma unroll
    for (int c = 0; c < 4; ++c) af[g][c] = zero4;
  }

  unsigned long long mwA[4], mwB[4];
  uint4 uA[2], vA[2], uB[2], vB[2];
  f16x8 bvA[2][4], bvB[2][4];

  issue_loads(0, i0, r, kg, mrowT, up, vp, hp, mwA, uA, vA, bvA);
  for (int j64 = 0; j64 < N_; j64 += 128) {
    issue_loads(j64 + 64, i0, r, kg, mrowT, up, vp, hp, mwB, uB, vB, bvB);
    compute_tile(mwA, uA, vA, bvA, Apk, Cpk, kg, af, as_, onesv);
    if (j64 + 128 < N_)
      issue_loads(j64 + 128, i0, r, kg, mrowT, up, vp, hp, mwA, uA, vA, bvA);
    compute_tile(mwB, uB, vB, bvB, Apk, Cpk, kg, af, as_, onesv);
  }

  // epilogue: D row = kg*4+reg (i within group), col = r (f within c-block)
  float bias_c[4];
#pragma unroll
  for (int c = 0; c < 4; ++c) bias_c[c] = BIAS[h * 64 + c * 16 + r];
#pragma unroll
  for (int g = 0; g < 4; ++g) {
#pragma unroll
    for (int reg = 0; reg < 4; ++reg) {
      const int ir = i0 + g * 16 + kg * 4 + reg;
      const float inv = 1.0f / as_[g][reg];
#pragma unroll
      for (int c = 0; c < 4; ++c) {
        const int f = h * 64 + c * 16 + r;
        const size_t off = (size_t)(b * N_ + ir) * OUTF_ + f;
        float o = af[g][c][reg] * inv + bias_c[c] + X[off];
        o = o > 0.f ? o : __expf(o) - 1.f;
        OUT[off] = o;
      }
    }
  }
}

extern "C" void kernel_launch(void* const* d_in, const int* in_sizes, int n_in,
                              void* d_out, int out_size, void* d_ws, size_t ws_size,
                              hipStream_t stream) {
  const float* ADJ  = (const float*)d_in[0];
  const float* X    = (const float*)d_in[1];
  const float* W    = (const float*)d_in[2];
  const float* AL   = (const float*)d_in[3];
  const float* AR   = (const float*)d_in[4];
  const float* BIAS = (const float*)d_in[5];
  float* OUT = (float*)d_out;

  char* ws = (char*)d_ws;
  size_t off = 0;
  _Float16* HbT = (_Float16*)(ws + off); off += (size_t)B_ * 4 * 64 * N_ * 2;      // 16 MiB
  _Float16* WT  = (_Float16*)(ws + off); off += (size_t)K_ * OUTF_ * 2;            // 128 KiB
  float* ELt    = (float*)(ws + off);    off += (size_t)B_ * 4 * N_ * 4;           // 512 KiB
  float* ERt    = (float*)(ws + off);    off += (size_t)B_ * 4 * N_ * 4;           // 512 KiB
  _Float16* UH  = (_Float16*)(ws + off); off += (size_t)B_ * 4 * N_ * 2;           // 256 KiB
  _Float16* VH  = (_Float16*)(ws + off); off += (size_t)B_ * 4 * N_ * 2;
  float2* ACb   = (float2*)(ws + off);   off += (size_t)B_ * 4 * N_ * 8;           // 1 MiB
  unsigned long long* MASKT = (unsigned long long*)(ws + off);                      // 4 MiB

  k_wt<<<256, 256, 0, stream>>>(W, WT);
  k_maskT<<<8192, 256, 0, stream>>>(ADJ, MASKT);
  k_gemm_h<<<512, 256, 0, stream>>>(X, WT, AL, AR, HbT, ELt, ERt, UH, VH);
  k_acprep<<<128, 256, 0, stream>>>(ERt, ELt, ACb);
  k_agg<<<512, 256, 0, stream>>>(HbT, UH, VH, ACb, MASKT, X, BIAS, OUT);
}

// Round 7
// 119.033 us; speedup vs baseline: 10.0957x; 1.1010x over previous
//
#include <hip/hip_runtime.h>
#include <hip/hip_fp16.h>
#include <stdint.h>

#define B_    32
#define N_    1024
#define K_    256
#define OUTF_ 256

typedef __attribute__((ext_vector_type(4))) float f32x4;
typedef __attribute__((ext_vector_type(8))) _Float16 f16x8;

__device__ __forceinline__ float lrelu(float z) { return z > 0.f ? z : 0.2f * z; }

__device__ __forceinline__ unsigned int pk2(float x) {
  unsigned int u = (unsigned int)__half_as_ushort(__float2half(x));
  return u | (u << 16);
}
__device__ __forceinline__ unsigned int pkmul(unsigned int a, unsigned int b) {
  union { unsigned int u; __half2 h; } A, Bv, R;
  A.u = a; Bv.u = b; R.h = __hmul2(A.h, Bv.h); return R.u;
}
__device__ __forceinline__ unsigned int pkmax(unsigned int a, unsigned int b) {
  unsigned int r;
  asm("v_pk_max_f16 %0, %1, %2" : "=v"(r) : "v"(a), "v"(b));
  return r;
}

// ---------------- prep: W[k][f] f32 -> WT[f][k] f16 ----------------
__global__ __launch_bounds__(256) void k_wt(const float* __restrict__ W,
                                            _Float16* __restrict__ WT) {
  const int k = blockIdx.x, f = threadIdx.x;
  WT[(size_t)f * K_ + k] = (_Float16)W[(size_t)k * OUTF_ + f];
}

// ---------------- adj -> transposed bitmask MASKT[b][jw][i] (u64 of 64 j-bits) -------------
__global__ __launch_bounds__(256) void k_maskT(const float* __restrict__ ADJ,
                                               unsigned long long* __restrict__ MASKT) {
  const int t = threadIdx.x, lane = t & 63, w = t >> 6;
  const int row = blockIdx.x * 4 + w;          // b*N + i
  const int b = row >> 10, i = row & (N_ - 1);
  const float* arow = ADJ + (size_t)row * N_;
#pragma unroll
  for (int jw = 0; jw < 16; ++jw) {
    const unsigned long long bits = __ballot(arow[jw * 64 + lane] > 0.5f);
    if (lane == 0) MASKT[((size_t)b * 16 + jw) * N_ + i] = bits;
  }
}

// ---------------- MFMA f16 GEMM: H = X @ W -> HbT[bh][f=64][j=N] f16 (transposed),
// fused el/er -> ELt/ERt f32, and u=e^er, v=e^{0.2 er} f16. ----------------
__global__ __launch_bounds__(256) void k_gemm_h(
    const float* __restrict__ X, const _Float16* __restrict__ WT,
    const float* __restrict__ AL, const float* __restrict__ AR,
    _Float16* __restrict__ HbT, float* __restrict__ ELt, float* __restrict__ ERt,
    _Float16* __restrict__ UH, _Float16* __restrict__ VH) {
  const int t = threadIdx.x, lane = t & 63, w = t >> 6;
  const int r = lane & 15, kg = lane >> 4;
  const int i0 = blockIdx.x * 64 + w * 16;   // 64-row tiles never cross a batch
  const int b = i0 >> 10;
  const int ib = i0 & (N_ - 1);

  f32x4 acc[16];
#pragma unroll
  for (int c = 0; c < 16; ++c) acc[c] = (f32x4){0.f, 0.f, 0.f, 0.f};

  const float* xrow = X + (size_t)(i0 + r) * K_;
#pragma unroll
  for (int ks = 0; ks < 8; ++ks) {
    const int k0 = ks * 32 + kg * 8;
    const float4 xa = *(const float4*)&xrow[k0];
    const float4 xb = *(const float4*)&xrow[k0 + 4];
    f16x8 a;
    a[0] = (_Float16)xa.x; a[1] = (_Float16)xa.y; a[2] = (_Float16)xa.z; a[3] = (_Float16)xa.w;
    a[4] = (_Float16)xb.x; a[5] = (_Float16)xb.y; a[6] = (_Float16)xb.z; a[7] = (_Float16)xb.w;
#pragma unroll
    for (int c = 0; c < 16; ++c) {
      const f16x8 bv = *(const f16x8*)&WT[(size_t)(c * 16 + r) * K_ + k0];
      acc[c] = __builtin_amdgcn_mfma_f32_16x16x32_f16(a, bv, acc[c], 0, 0, 0);
    }
  }
  // fused el/er
  float el[4][4] = {}, er[4][4] = {};
#pragma unroll
  for (int c = 0; c < 16; ++c) {
    const float al = AL[c * 16 + r], ar = AR[c * 16 + r];
    const int hh = c >> 2;
#pragma unroll
    for (int reg = 0; reg < 4; ++reg) {
      el[hh][reg] = fmaf(acc[c][reg], al, el[hh][reg]);
      er[hh][reg] = fmaf(acc[c][reg], ar, er[hh][reg]);
    }
  }
#pragma unroll
  for (int s = 1; s < 16; s <<= 1) {
#pragma unroll
    for (int hh = 0; hh < 4; ++hh)
#pragma unroll
      for (int reg = 0; reg < 4; ++reg) {
        el[hh][reg] += __shfl_xor(el[hh][reg], s);
        er[hh][reg] += __shfl_xor(er[hh][reg], s);
      }
  }
  if (r == 0) {
#pragma unroll
    for (int hh = 0; hh < 4; ++hh) {
      const int bh = b * 4 + hh;
#pragma unroll
      for (int reg = 0; reg < 4; ++reg) {
        const int ii = ib + kg * 4 + reg;
        const float e_l = el[hh][reg], e_r = er[hh][reg];
        ELt[(size_t)bh * N_ + ii] = e_l;
        ERt[(size_t)bh * N_ + ii] = e_r;
        UH[(size_t)bh * N_ + ii]  = (_Float16)__expf(e_r);
        VH[(size_t)bh * N_ + ii]  = (_Float16)__expf(0.2f * e_r);
      }
    }
  }
  // transposed f16 store
#pragma unroll
  for (int c = 0; c < 16; ++c) {
    const int bh = b * 4 + (c >> 2);
    const int fin = (c & 3) * 16 + r;
    union { _Float16 h[4]; ushort4 u; } pk;
#pragma unroll
    for (int reg = 0; reg < 4; ++reg) pk.h[reg] = (_Float16)acc[c][reg];
    *(ushort4*)&HbT[(size_t)bh * (64 * N_) + (size_t)fin * N_ + ib + kg * 4] = pk.u;
  }
}

// ---------------- fused: per-(b,h) er max + per-row A=e^{el-m}, C=e^{0.2el-m} ----------------
__global__ __launch_bounds__(256) void k_acprep(const float* __restrict__ ERt,
                                                const float* __restrict__ ELt,
                                                float2* __restrict__ ACb) {
  __shared__ float red[4];
  const int bh = blockIdx.x, t = threadIdx.x, lane = t & 63, w = t >> 6;
  const float4 v = *(const float4*)&ERt[(size_t)bh * N_ + t * 4];
  float mx = fmaxf(fmaxf(v.x, v.y), fmaxf(v.z, v.w));
#pragma unroll
  for (int s = 32; s > 0; s >>= 1) mx = fmaxf(mx, __shfl_xor(mx, s));
  if (lane == 0) red[w] = mx;
  __syncthreads();
  const float ermax = fmaxf(fmaxf(red[0], red[1]), fmaxf(red[2], red[3]));
  const float4 el4 = *(const float4*)&ELt[(size_t)bh * N_ + t * 4];
  const float els[4] = {el4.x, el4.y, el4.z, el4.w};
#pragma unroll
  for (int q = 0; q < 4; ++q) {
    const float m = lrelu(els[q] + ermax);
    ACb[(size_t)bh * N_ + t * 4 + q] = make_float2(__expf(els[q] - m), __expf(0.2f * els[q] - m));
  }
}

// ---------------- k_agg v3: LDS-staged MFMA aggregation ----------------
// Block = (b, h, 128 i-rows), 4 waves x 32 i (2 groups). Per 64-j phase the block
// stages the shared 8KB H-panel once via global_load_lds into a source-permuted
// LINEAR LDS layout [c][half][r][kg][16B] -> each ds_read_b128 is a dense 1KB
// wave read with immediate offsets. Double-buffered; u/v/mask prefetched in regs.
struct UV { uint4 ul, uh, vl, vh; unsigned long long m0, m1; };

__global__ __launch_bounds__(256, 3) void k_agg(
    const _Float16* __restrict__ HbT, const _Float16* __restrict__ UH,
    const _Float16* __restrict__ VH, const float2* __restrict__ ACb,
    const unsigned long long* __restrict__ MASKT,
    const float* __restrict__ X, const float* __restrict__ BIAS,
    float* __restrict__ OUT) {
  __shared__ __align__(16) char smem[16384];
  const int t = threadIdx.x, lane = t & 63, w = t >> 6;
  const int bid = blockIdx.x;
  const int b = bid & 31, h = (bid >> 5) & 3, it = bid >> 7;   // it in 0..7
  const int bh = b * 4 + h;
  const int i0 = it * 128 + w * 32;
  const int r = lane & 15, kg = lane >> 4;
  const int lbase = r * 64 + kg * 16;                          // LDS read base (bytes)

  // staging source decode for LDS byte p = q*4096 + t*16:
  // c=p>>11, half=(p>>10)&1, rr=(p>>6)&15, kg=(p>>4)&3 -> f=c*16+rr, jj=half*32+kg*8
  const int f_s  = ((t >> 7) << 4) + ((t >> 2) & 15);
  const int jj_s = (((t >> 6) & 1) << 5) + ((t & 3) << 3);
  const _Float16* hp = HbT + (size_t)bh * (64 * N_);
  const _Float16* src0 = hp + (size_t)f_s * N_ + jj_s;
  const _Float16* src1 = hp + (size_t)(f_s + 32) * N_ + jj_s;

  unsigned int Apk[2], Cpk[2];
#pragma unroll
  for (int g = 0; g < 2; ++g) {
    const float2 ac = ACb[(size_t)bh * N_ + i0 + g * 16 + r];
    Apk[g] = pk2(ac.x); Cpk[g] = pk2(ac.y);
  }
  const unsigned long long* mrowT = MASKT + (size_t)b * 16 * N_;
  const _Float16* up = UH + (size_t)bh * N_;
  const _Float16* vp = VH + (size_t)bh * N_;

  f16x8 onesv;
#pragma unroll
  for (int e = 0; e < 8; ++e) onesv[e] = (_Float16)1.0f;

  const f32x4 zero4 = {0.f, 0.f, 0.f, 0.f};
  f32x4 af[2][4], as_[2];
#pragma unroll
  for (int g = 0; g < 2; ++g) {
    as_[g] = zero4;
#pragma unroll
    for (int c = 0; c < 4; ++c) af[g][c] = zero4;
  }

#define STAGE(BUF, j) do {                                                              \
    __builtin_amdgcn_global_load_lds(                                                   \
        (const __attribute__((address_space(1))) void*)(src0 + (j)),                    \
        (__attribute__((address_space(3))) void*)(smem + (BUF) + w * 1024), 16, 0, 0);  \
    __builtin_amdgcn_global_load_lds(                                                   \
        (const __attribute__((address_space(1))) void*)(src1 + (j)),                    \
        (__attribute__((address_space(3))) void*)(smem + (BUF) + 4096 + w * 1024),      \
        16, 0, 0);                                                                      \
  } while (0)

#define UVL(S, j) do {                                                                  \
    const int jl_ = (j) + kg * 8;                                                       \
    S.ul = *(const uint4*)&up[jl_];  S.uh = *(const uint4*)&up[jl_ + 32];               \
    S.vl = *(const uint4*)&vp[jl_];  S.vh = *(const uint4*)&vp[jl_ + 32];               \
    const size_t mo_ = (size_t)((j) >> 6) * N_ + i0 + r;                                \
    S.m0 = mrowT[mo_]; S.m1 = mrowT[mo_ + 16];                                          \
  } while (0)

#define COMPUTE(BUF, S) do {                                                            \
    f16x8 bvv[2][4];                                                                    \
    _Pragma("unroll") for (int half = 0; half < 2; ++half)                              \
    _Pragma("unroll") for (int c = 0; c < 4; ++c)                                       \
      bvv[half][c] = *(const f16x8*)(smem + (BUF) + half * 1024 + c * 2048 + lbase);    \
    _Pragma("unroll") for (int half = 0; half < 2; ++half) {                            \
      const uint4 uu = half ? S.uh : S.ul;                                              \
      const uint4 vv = half ? S.vh : S.vl;                                              \
      _Pragma("unroll") for (int g = 0; g < 2; ++g) {                                   \
        const unsigned long long mwg = g ? S.m1 : S.m0;                                 \
        const unsigned int bits = (unsigned int)(mwg >> (half * 32 + kg * 8)) & 0xffu;  \
        union { unsigned int u[4]; f16x8 v; } a;                                        \
        _Pragma("unroll") for (int pp = 0; pp < 4; ++pp) {                              \
          const unsigned int ml = (unsigned int)((int)(bits << (31 - 2 * pp)) >> 31);   \
          const unsigned int mh = (unsigned int)((int)(bits << (30 - 2 * pp)) >> 31);   \
          const unsigned int mp = (mh & 0xFFFF0000u) | (ml & 0xFFFFu);                  \
          const unsigned int pu = pkmul(Apk[g], ((const unsigned int*)&uu)[pp]);        \
          const unsigned int pv = pkmul(Cpk[g], ((const unsigned int*)&vv)[pp]);        \
          a.u[pp] = pkmax(pu, pv) & mp;                                                 \
        }                                                                               \
        _Pragma("unroll") for (int c = 0; c < 4; ++c)                                   \
          af[g][c] = __builtin_amdgcn_mfma_f32_16x16x32_f16(a.v, bvv[half][c],          \
                                                            af[g][c], 0, 0, 0);        \
        as_[g] = __builtin_amdgcn_mfma_f32_16x16x32_f16(a.v, onesv, as_[g], 0, 0, 0);   \
      }                                                                                 \
    }                                                                                   \
  } while (0)

  UV rA, rB;
  STAGE(0, 0);
  UVL(rA, 0);
  UVL(rB, 64);

  for (int jp = 0; jp < 8; ++jp) {
    const int jA = jp * 128, jB = jA + 64;
    __syncthreads();                       // drains vmcnt: bufA staged, rA/rB ready
    STAGE(8192, jB);                       // stage next phase's panel into bufB
    COMPUTE(0, rA);
    UVL(rA, (jA + 128) & (N_ - 1));        // prefetch regs for next phase-A
    __syncthreads();
    STAGE(0, (jA + 128) & (N_ - 1));       // stage next phase-A panel into bufA
    COMPUTE(8192, rB);
    UVL(rB, (jB + 128) & (N_ - 1));        // prefetch regs for next phase-B
  }

#undef STAGE
#undef UVL
#undef COMPUTE

  // epilogue: D row = kg*4+reg (i within group), col = r (f within c-block)
  float bias_c[4];
#pragma unroll
  for (int c = 0; c < 4; ++c) bias_c[c] = BIAS[h * 64 + c * 16 + r];
#pragma unroll
  for (int g = 0; g < 2; ++g) {
#pragma unroll
    for (int reg = 0; reg < 4; ++reg) {
      const int ir = i0 + g * 16 + kg * 4 + reg;
      const float inv = 1.0f / as_[g][reg];
#pragma unroll
      for (int c = 0; c < 4; ++c) {
        const int f = h * 64 + c * 16 + r;
        const size_t off = (size_t)(b * N_ + ir) * OUTF_ + f;
        float o = af[g][c][reg] * inv + bias_c[c] + X[off];
        o = o > 0.f ? o : __expf(o) - 1.f;
        OUT[off] = o;
      }
    }
  }
}

extern "C" void kernel_launch(void* const* d_in, const int* in_sizes, int n_in,
                              void* d_out, int out_size, void* d_ws, size_t ws_size,
                              hipStream_t stream) {
  const float* ADJ  = (const float*)d_in[0];
  const float* X    = (const float*)d_in[1];
  const float* W    = (const float*)d_in[2];
  const float* AL   = (const float*)d_in[3];
  const float* AR   = (const float*)d_in[4];
  const float* BIAS = (const float*)d_in[5];
  float* OUT = (float*)d_out;

  char* ws = (char*)d_ws;
  size_t off = 0;
  _Float16* HbT = (_Float16*)(ws + off); off += (size_t)B_ * 4 * 64 * N_ * 2;      // 16 MiB
  _Float16* WT  = (_Float16*)(ws + off); off += (size_t)K_ * OUTF_ * 2;            // 128 KiB
  float* ELt    = (float*)(ws + off);    off += (size_t)B_ * 4 * N_ * 4;           // 512 KiB
  float* ERt    = (float*)(ws + off);    off += (size_t)B_ * 4 * N_ * 4;           // 512 KiB
  _Float16* UH  = (_Float16*)(ws + off); off += (size_t)B_ * 4 * N_ * 2;           // 256 KiB
  _Float16* VH  = (_Float16*)(ws + off); off += (size_t)B_ * 4 * N_ * 2;
  float2* ACb   = (float2*)(ws + off);   off += (size_t)B_ * 4 * N_ * 8;           // 1 MiB
  unsigned long long* MASKT = (unsigned long long*)(ws + off);                      // 4 MiB

  k_wt<<<256, 256, 0, stream>>>(W, WT);
  k_maskT<<<8192, 256, 0, stream>>>(ADJ, MASKT);
  k_gemm_h<<<512, 256, 0, stream>>>(X, WT, AL, AR, HbT, ELt, ERt, UH, VH);
  k_acprep<<<128, 256, 0, stream>>>(ERt, ELt, ACb);
  k_agg<<<1024, 256, 0, stream>>>(HbT, UH, VH, ACb, MASKT, X, BIAS, OUT);
}